// Round 8
// baseline (757.021 us; speedup 1.0000x reference)
//
#include <hip/hip_runtime.h>

#define NN   32768
#define NV   64
#define E0E  524288
#define HID  128
#define NL   4
#define NH   8
#define DH   16
#define SCALE 0.25f
#define LDA  136   // bf16 row stride for staged A in k_post (16B frag reads, 2-way alias)
#define LDA2 132   // ushort stride for gproj 128-row planes (264B = 2-bank shift/row)
#define CAP0 64
#define CAP1 1024

typedef __attribute__((ext_vector_type(8))) short short8;   // 8 bf16 = 4 VGPRs
typedef __attribute__((ext_vector_type(4))) float f32x4;

__device__ __forceinline__ float gelu_f(float x) {
  return 0.5f * x * (1.0f + erff(x * 0.7071067811865475f));
}
__device__ __forceinline__ float sigmoid_f(float x) {
  return 1.0f / (1.0f + __expf(-x));
}
__device__ __forceinline__ unsigned short f2bf(float x) {   // RN-even f32->bf16
  unsigned u = __float_as_uint(x);
  return (unsigned short)((u + 0x7FFFu + ((u >> 16) & 1u)) >> 16);
}
__device__ __forceinline__ float bf2f(unsigned short h) {
  return __uint_as_float(((unsigned)h) << 16);
}
__device__ __forceinline__ unsigned short f2h(float x) {
  union { _Float16 h; unsigned short u; } cv;
  cv.h = (_Float16)x;
  return cv.u;
}
__device__ __forceinline__ float h2f(unsigned short u) {
  union { _Float16 h; unsigned short u; } cv;
  cv.u = u;
  return (float)cv.h;
}
__device__ __forceinline__ float f16lo(unsigned u) { return h2f((unsigned short)(u & 0xffffu)); }
__device__ __forceinline__ float f16hi(unsigned u) { return h2f((unsigned short)(u >> 16)); }

union SMu {
  struct { unsigned short Ah[64][LDA]; unsigned short Al[64][LDA]; } a;  // 34816 B
  struct { float xr[HID]; float xn[HID]; } v;
};

union GSM {   // gproj LDS: full 128-row split planes (67584 B) | qv0 row
  struct { unsigned short Ah[128][LDA2]; unsigned short Al[128][LDA2]; } g;
  struct { float xr[HID]; } v;
};

// ---- stage 64xK=128 fp32 tile into split hi/lo bf16 LDS (k_post) ----
__device__ __forceinline__ void stage_A(unsigned short Ah[][LDA], unsigned short Al[][LDA],
                                        int t, const float* __restrict__ A, int m0, int gelu) {
  #pragma unroll
  for (int i = 0; i < 8; ++i) {
    int idx = t + 256 * i;            // float4 index over 64x32
    int m = idx >> 5, c4 = (idx & 31) * 4;
    float4 v = *(const float4*)(A + (size_t)(m0 + m) * HID + c4);
    if (gelu) { v.x = gelu_f(v.x); v.y = gelu_f(v.y); v.z = gelu_f(v.z); v.w = gelu_f(v.w); }
    unsigned short h0 = f2bf(v.x), h1 = f2bf(v.y), h2 = f2bf(v.z), h3 = f2bf(v.w);
    *(ushort4*)&Ah[m][c4] = make_ushort4(h0, h1, h2, h3);
    *(ushort4*)&Al[m][c4] = make_ushort4(f2bf(v.x - bf2f(h0)), f2bf(v.y - bf2f(h1)),
                                         f2bf(v.z - bf2f(h2)), f2bf(v.w - bf2f(h3)));
  }
}

// ---- MFMA split-bf16 pass over 64x128 tile (k_post post-GEMM) ----
__device__ __forceinline__ void mfma_pass(const unsigned short Ah[][LDA],
    const unsigned short Al[][LDA], int t, const unsigned short* __restrict__ Wf,
    f32x4 acc[2][4]) {
  const int w = t >> 6, lane = t & 63, c16 = lane & 15, quad = lane >> 4;
  #pragma unroll
  for (int ks = 0; ks < 4; ++ks) {
    short8 ah[4], al[4];
    #pragma unroll
    for (int s = 0; s < 4; ++s) {
      ah[s] = *(const short8*)&Ah[16 * s + c16][ks * 32 + quad * 8];
      al[s] = *(const short8*)&Al[16 * s + c16][ks * 32 + quad * 8];
    }
    #pragma unroll
    for (int j = 0; j < 2; ++j) {
      const unsigned short* bp = Wf + (size_t)(((2 * w + j) * 4 + ks) * 64 + lane) * 8;
      short8 bh = *(const short8*)bp;
      short8 bl = *(const short8*)(bp + 16384);
      #pragma unroll
      for (int s = 0; s < 4; ++s) {
        acc[j][s] = __builtin_amdgcn_mfma_f32_16x16x32_bf16(ah[s], bh, acc[j][s], 0, 0, 0);
        acc[j][s] = __builtin_amdgcn_mfma_f32_16x16x32_bf16(ah[s], bl, acc[j][s], 0, 0, 0);
        acc[j][s] = __builtin_amdgcn_mfma_f32_16x16x32_bf16(al[s], bh, acc[j][s], 0, 0, 0);
      }
    }
  }
}

// ---- gproj body: 128x128 output tile, K=128 split-bf16, one weight slice ----
// r7 lesson: slice WITHOUT redundancy. A staged once (1 barrier), then a barrier-free k-loop;
// each wave owns a 64x64 quadrant (4x4 frags, 192 MFMA). B frags read from L2-hot frag-order
// FW (same layout as mfma_pass -> no k_frag change). Slices nt: 0=q(fp32), 1..4=K0,V0,K1,V1
// (fp16 2-byte stores into disjoint halves of interleaved Pkv dwords -> k_edges unchanged).
__device__ void gproj_body(unsigned short Ah[][LDA2], unsigned short Al[][LDA2], int t,
                           const float* __restrict__ A, int m0,
                           const unsigned short* __restrict__ FW, int l, int nt,
                           const float* __restrict__ bq0, const float* __restrict__ CBl,
                           float* __restrict__ Pq, unsigned int* __restrict__ Pkv0,
                           unsigned int* __restrict__ Pkv1) {
  #pragma unroll
  for (int i = 0; i < 16; ++i) {
    int idx = t + 256 * i;            // float4 index over 128x32
    int m = idx >> 5, c4 = (idx & 31) * 4;
    float4 v = *(const float4*)(A + (size_t)(m0 + m) * HID + c4);
    unsigned short h0 = f2bf(v.x), h1 = f2bf(v.y), h2 = f2bf(v.z), h3 = f2bf(v.w);
    *(ushort4*)&Ah[m][c4] = make_ushort4(h0, h1, h2, h3);
    *(ushort4*)&Al[m][c4] = make_ushort4(f2bf(v.x - bf2f(h0)), f2bf(v.y - bf2f(h1)),
                                         f2bf(v.z - bf2f(h2)), f2bf(v.w - bf2f(h3)));
  }
  __syncthreads();
  const unsigned short* Wf = (nt == 0) ? FW + (size_t)(16 + l) * 32768
                                       : FW + (size_t)(l * 4 + nt - 1) * 32768;
  const int w = t >> 6, lane = t & 63, c16 = lane & 15, quad = lane >> 4;
  const int mh = (w >> 1) * 64, nfo = (w & 1) * 4;   // wave quadrant
  f32x4 acc[4][4] = {};
  #pragma unroll
  for (int ks = 0; ks < 4; ++ks) {
    short8 ah[4], al[4];
    #pragma unroll
    for (int mf = 0; mf < 4; ++mf) {
      ah[mf] = *(const short8*)&Ah[mh + mf * 16 + c16][ks * 32 + quad * 8];
      al[mf] = *(const short8*)&Al[mh + mf * 16 + c16][ks * 32 + quad * 8];
    }
    #pragma unroll
    for (int nf = 0; nf < 4; ++nf) {
      const unsigned short* bp = Wf + (size_t)(((nfo + nf) * 4 + ks) * 64 + lane) * 8;
      short8 bh = *(const short8*)bp;
      short8 bl = *(const short8*)(bp + 16384);
      #pragma unroll
      for (int mf = 0; mf < 4; ++mf) {
        acc[mf][nf] = __builtin_amdgcn_mfma_f32_16x16x32_bf16(ah[mf], bh, acc[mf][nf], 0, 0, 0);
        acc[mf][nf] = __builtin_amdgcn_mfma_f32_16x16x32_bf16(ah[mf], bl, acc[mf][nf], 0, 0, 0);
        acc[mf][nf] = __builtin_amdgcn_mfma_f32_16x16x32_bf16(al[mf], bh, acc[mf][nf], 0, 0, 0);
      }
    }
  }
  if (nt == 0) {
    #pragma unroll
    for (int nf = 0; nf < 4; ++nf) {
      const int col = (nfo + nf) * 16 + c16;
      const float bb = bq0[col];
      #pragma unroll
      for (int mf = 0; mf < 4; ++mf)
        #pragma unroll
        for (int r = 0; r < 4; ++r) {
          int row = m0 + mh + mf * 16 + quad * 4 + r;
          Pq[(size_t)row * HID + col] = acc[mf][nf][r] + bb;
        }
    }
  } else {
    const int mat = nt - 1;                 // 0:K0 1:V0 2:K1 3:V1
    const float* bb = CBl + mat * HID;
    unsigned short* dst = (unsigned short*)((mat >> 1) ? Pkv1 : Pkv0) + (mat & 1);
    #pragma unroll
    for (int nf = 0; nf < 4; ++nf) {
      const int col = (nfo + nf) * 16 + c16;
      const float b = bb[col];
      #pragma unroll
      for (int mf = 0; mf < 4; ++mf)
        #pragma unroll
        for (int r = 0; r < 4; ++r) {
          int row = m0 + mh + mf * 16 + quad * 4 + r;
          dst[((size_t)row * HID + col) * 2] = f2h(acc[mf][nf][r] + b);
        }
    }
  }
}

// ================= k_setup: weight-combine only (16 blocks) ===================================
__global__ __launch_bounds__(256) void k_setup(
    const float* __restrict__ Wk, const float* __restrict__ Wv,
    const float* __restrict__ bk, const float* __restrict__ bv,
    const float* __restrict__ a_rel, const float* __restrict__ m_rel,
    const float* __restrict__ p_rel,
    float* __restrict__ CW, float* __restrict__ CB) {
  int blk = blockIdx.x, t = threadIdx.x;   // 0..15: l*4 + {K0,V0,K1,V1}
  int l = blk >> 2, mat = blk & 3;
  int rel = mat >> 1;
  int isK = ((mat & 1) == 0);
  const float* W  = (isK ? Wk : Wv) + (size_t)(l * 2) * HID * HID;
  const float* bb = (isK ? bk : bv) + (l * 2) * HID;
  const float* R  = (isK ? a_rel : m_rel) + (size_t)((l * 2 + rel) * NH) * DH * DH;
  float* cw = CW + (size_t)blk * HID * HID;
  float* cb = CB + blk * HID;
  for (int o = t; o < HID * HID; o += 256) {
    int j = o >> 7, c = o & 127;
    int h = j >> 4, e = j & 15;
    float sc = isK ? (p_rel[(l * 2 + rel) * NH + h] * SCALE) : 1.0f;
    float s = 0.f;
    #pragma unroll
    for (int d = 0; d < DH; ++d)
      s += W[(size_t)(h * DH + d) * HID + c] * R[h * 256 + d * 16 + e];
    cw[(size_t)j * HID + c] = s * sc;   // [n][k]
  }
  if (t < HID) {
    int j = t, h = j >> 4, e = j & 15;
    float sc = isK ? (p_rel[(l * 2 + rel) * NH + h] * SCALE) : 1.0f;
    float s = 0.f;
    #pragma unroll
    for (int d = 0; d < DH; ++d) s += bb[h * DH + d] * R[h * 256 + d * 16 + e];
    cb[j] = s * sc;
  }
}

// ================= frag-order + split all 24 weight mats (CW 0-15, Wq0 16-19, Wa0 20-23) ======
__global__ __launch_bounds__(256) void k_frag(const float* __restrict__ CW,
                                              const float* __restrict__ Wq,
                                              const float* __restrict__ Wa,
                                              unsigned short* __restrict__ FW) {
  int m = blockIdx.x, t = threadIdx.x;
  const float* src = (m < 16) ? (CW + (size_t)m * HID * HID)
                   : (m < 20) ? (Wq + (size_t)((m - 16) * 2) * HID * HID)
                              : (Wa + (size_t)((m - 20) * 2) * HID * HID);
  unsigned short* hi = FW + (size_t)m * 32768;
  unsigned short* lo = hi + 16384;
  for (int idx = t; idx < 16384; idx += 256) {
    int j = idx & 7, lane = (idx >> 3) & 63, ks = (idx >> 9) & 3, nt = idx >> 11;
    int n = nt * 16 + (lane & 15);
    int k = ks * 32 + (lane >> 4) * 8 + j;
    float x = src[(size_t)n * HID + k];
    unsigned short h = f2bf(x);
    hi[idx] = h;
    lo[idx] = f2bf(x - bf2f(h));
  }
}

// ================= k_pre: bucket scatter + layer-0 gproj (5 slices) + qv0, one launch =========
struct PreArgs {
  const int *src0, *dst0, *src1, *dst1;
  int *cnt0, *cnt1, *colB0, *colB1;
  const float* x_op; const unsigned short* FW; const float *bq, *CB;
  float* Pq; unsigned int *Pkv0, *Pkv1;
  const float *x_v, *Wq1, *bq1; float* qv;
};

__launch_bounds__(256)
__global__ void k_pre(PreArgs a) {
  __shared__ GSM sm;
  int bx = blockIdx.x, t = threadIdx.x;
  if (bx < E0E / 1024) {                     // edge0 bucket scatter (4 edges/thread ILP)
    int base = bx * 1024 + t;
    #pragma unroll
    for (int i = 0; i < 4; ++i) {
      int e = base + i * 256;
      int d = a.dst0[e];
      int pos = atomicAdd(&a.cnt0[d], 1);
      if (pos < CAP0) a.colB0[((size_t)d << 6) + pos] = a.src0[e];
    }
    return;
  }
  bx -= E0E / 1024;
  if (bx < NN / 1024) {                      // edge1 bucket scatter
    int base = bx * 1024 + t;
    #pragma unroll
    for (int i = 0; i < 4; ++i) {
      int e = base + i * 256;
      int d = a.dst1[e];
      int pos = atomicAdd(&a.cnt1[d], 1);
      if (pos < CAP1) a.colB1[((size_t)d << 10) + pos] = a.src1[e];
    }
    return;
  }
  bx -= NN / 1024;
  if (bx < 5 * (NN / 128)) {                 // layer-0 projections: mt-major (5 slices adjacent
    int mt = bx / 5, nt = bx % 5;            //  -> same A-tile L2-resident across slices)
    gproj_body(sm.g.Ah, sm.g.Al, t, a.x_op, mt * 128, a.FW, 0, nt, a.bq, a.CB,
               a.Pq, a.Pkv0, a.Pkv1);
    return;
  }
  bx -= 5 * (NN / 128);                      // qv0 for vnode bx
  if (t < HID) sm.v.xr[t] = a.x_v[bx * HID + t];
  __syncthreads();
  if (t < HID) {
    float s = a.bq1[t];
    const float4* wr = (const float4*)(a.Wq1 + (size_t)t * HID);
    const float4* xx = (const float4*)sm.v.xr;
    #pragma unroll 8
    for (int c = 0; c < HID / 4; ++c) {
      float4 w4 = wr[c], x4 = xx[c];
      s += x4.x * w4.x + x4.y * w4.y + x4.z * w4.z + x4.w * w4.w;
    }
    a.qv[bx * HID + t] = s;
  }
}

// ================= k_gproj: standalone per-layer projection GEMM ==============================
__launch_bounds__(256)
__global__ void k_gproj(const float* __restrict__ A, const unsigned short* __restrict__ FW,
                        const float* __restrict__ bq0, const float* __restrict__ CBl,
                        float* __restrict__ Pq, unsigned int* __restrict__ Pkv0,
                        unsigned int* __restrict__ Pkv1, int l, int nt_base, int ntn) {
  __shared__ GSM sm;
  int mt = blockIdx.x / ntn, nt = nt_base + blockIdx.x % ntn;
  gproj_body(sm.g.Ah, sm.g.Al, threadIdx.x, A, mt * 128, FW, l, nt, bq0, CBl, Pq, Pkv0, Pkv1);
}

// ================= k_edges: edge0 (blocks < e0blocks; DEAD at l=3) + edge1 =====================
__launch_bounds__(256)
__global__ void k_edges(const float* __restrict__ Pq, const unsigned int* __restrict__ Pkv0,
                        const unsigned int* __restrict__ Pkv1,
                        const int* __restrict__ cnt0, const int* __restrict__ colB0,
                        float* __restrict__ agg, const float* __restrict__ qv,
                        const int* __restrict__ cnt1, const int* __restrict__ colB1,
                        float* __restrict__ part, int e0blocks) {
  int lane = threadIdx.x & 63;
  if (blockIdx.x < e0blocks) {
    int n = blockIdx.x * 4 + (threadIdx.x >> 6);
    float2 q = *(const float2*)(Pq + (size_t)n * HID + 2 * lane);
    int cnt = cnt0[n]; if (cnt > CAP0) cnt = CAP0;
    int e = n << 6, e1 = (n << 6) + cnt;
    float acc0 = 0.f, acc1 = 0.f, wsum = 0.f;
    for (; e + 8 <= e1; e += 8) {
      const uint2* r[8];
      #pragma unroll
      for (int u = 0; u < 8; ++u)
        r[u] = (const uint2*)(Pkv0 + ((size_t)colB0[e + u] << 7) + 2 * lane);
      uint2 kv[8];
      #pragma unroll
      for (int u = 0; u < 8; ++u) kv[u] = *r[u];
      float p[8];
      #pragma unroll
      for (int u = 0; u < 8; ++u)
        p[u] = q.x * f16lo(kv[u].x) + q.y * f16lo(kv[u].y);
      #pragma unroll
      for (int u = 0; u < 8; ++u) {
        p[u] += __shfl_xor(p[u], 1); p[u] += __shfl_xor(p[u], 2); p[u] += __shfl_xor(p[u], 4);
      }
      #pragma unroll
      for (int u = 0; u < 8; ++u) {
        float wg = __expf(p[u]);
        wsum += wg; acc0 += wg * f16hi(kv[u].x); acc1 += wg * f16hi(kv[u].y);
      }
    }
    for (; e < e1; ++e) {
      uint2 kv = *(const uint2*)(Pkv0 + ((size_t)colB0[e] << 7) + 2 * lane);
      float p = q.x * f16lo(kv.x) + q.y * f16lo(kv.y);
      p += __shfl_xor(p, 1); p += __shfl_xor(p, 2); p += __shfl_xor(p, 4);
      float wg = __expf(p);
      wsum += wg; acc0 += wg * f16hi(kv.x); acc1 += wg * f16hi(kv.y);
    }
    float inv = 1.0f / (wsum + 1e-16f);
    *(float2*)(agg + (size_t)n * HID + 2 * lane) = make_float2(acc0 * inv, acc1 * inv);
  } else {
    int b2 = blockIdx.x - e0blocks;
    int g = b2 >> 3, ch = b2 & 7;
    int w = threadIdx.x >> 6;
    int slot = ch * 4 + w;
    float2 q = *(const float2*)(qv + g * HID + 2 * lane);
    int tot = cnt1[g]; if (tot > CAP1) tot = CAP1;
    int base = g << 10;
    int len = (tot + 31) >> 5;
    int s0 = base + slot * len;
    int s1 = s0 + len; int lim = base + tot; if (s1 > lim) s1 = lim;
    float acc0 = 0.f, acc1 = 0.f, wsum = 0.f;
    int e = s0;
    for (; e + 4 <= s1; e += 4) {
      uint2 ka = *(const uint2*)(Pkv1 + ((size_t)colB1[e]     << 7) + 2 * lane);
      uint2 kb = *(const uint2*)(Pkv1 + ((size_t)colB1[e + 1] << 7) + 2 * lane);
      uint2 kc = *(const uint2*)(Pkv1 + ((size_t)colB1[e + 2] << 7) + 2 * lane);
      uint2 kd = *(const uint2*)(Pkv1 + ((size_t)colB1[e + 3] << 7) + 2 * lane);
      float pa = q.x * f16lo(ka.x) + q.y * f16lo(ka.y);
      float pb = q.x * f16lo(kb.x) + q.y * f16lo(kb.y);
      float pc = q.x * f16lo(kc.x) + q.y * f16lo(kc.y);
      float pd = q.x * f16lo(kd.x) + q.y * f16lo(kd.y);
      pa += __shfl_xor(pa, 1); pb += __shfl_xor(pb, 1); pc += __shfl_xor(pc, 1); pd += __shfl_xor(pd, 1);
      pa += __shfl_xor(pa, 2); pb += __shfl_xor(pb, 2); pc += __shfl_xor(pc, 2); pd += __shfl_xor(pd, 2);
      pa += __shfl_xor(pa, 4); pb += __shfl_xor(pb, 4); pc += __shfl_xor(pc, 4); pd += __shfl_xor(pd, 4);
      float wa = __expf(pa), wb = __expf(pb), wc = __expf(pc), wd = __expf(pd);
      wsum += (wa + wb) + (wc + wd);
      acc0 += wa * f16hi(ka.x) + wb * f16hi(kb.x) + wc * f16hi(kc.x) + wd * f16hi(kd.x);
      acc1 += wa * f16hi(ka.y) + wb * f16hi(kb.y) + wc * f16hi(kc.y) + wd * f16hi(kd.y);
    }
    for (; e < s1; ++e) {
      uint2 kv = *(const uint2*)(Pkv1 + ((size_t)colB1[e] << 7) + 2 * lane);
      float p = q.x * f16lo(kv.x) + q.y * f16lo(kv.y);
      p += __shfl_xor(p, 1); p += __shfl_xor(p, 2); p += __shfl_xor(p, 4);
      float ww = __expf(p);
      wsum += ww; acc0 += ww * f16hi(kv.x); acc1 += ww * f16hi(kv.y);
    }
    float* pp = part + (size_t)(g * 32 + slot) * 192;
    pp[lane] = acc0; pp[64 + lane] = acc1; pp[128 + lane] = wsum;
  }
}

// ================= k_post: post-GEMM + skip -> xop (no proj tail) + vnode tail =================
struct PArgs {
  const float *agg; const unsigned short *WaF_l; const float *ba_l0, *skip_l0, *xold;
  float *xop;
  const float *part, *Wa_l1, *ba_l1, *skip_l1, *xvold;
  float *xv, *outsv_l, *qv;
  const float *Wq_n1, *bq_n1;
  int do_qv, vonly;
};

__device__ __forceinline__ void vtail(SMu& sm, int t, int v, const PArgs& f) {
  if (t < 64) {
    float a0 = 0.f, a1 = 0.f, ws2 = 0.f;
    for (int s = 0; s < 32; ++s) {
      const float* p = f.part + (size_t)(v * 32 + s) * 192;
      a0 += p[t]; a1 += p[64 + t]; ws2 += p[128 + t];
    }
    float inv = 1.0f / (ws2 + 1e-16f);
    sm.v.xr[2 * t]     = gelu_f(a0 * inv);
    sm.v.xr[2 * t + 1] = gelu_f(a1 * inv);
  }
  __syncthreads();
  if (t < HID) {
    float s = f.ba_l1[t];
    const float4* wr = (const float4*)(f.Wa_l1 + (size_t)t * HID);
    const float4* xx = (const float4*)sm.v.xr;
    #pragma unroll 8
    for (int c = 0; c < HID / 4; ++c) {
      float4 w4 = wr[c], x4 = xx[c];
      s += x4.x * w4.x + x4.y * w4.y + x4.z * w4.z + x4.w * w4.w;
    }
    float gg = sigmoid_f(*f.skip_l1);
    float nv2 = gg * s + (1.f - gg) * f.xvold[v * HID + t];
    f.xv[v * HID + t] = nv2;
    f.outsv_l[v * HID + t] = nv2;
    sm.v.xn[t] = nv2;
  }
  __syncthreads();
  if (f.do_qv && t < HID) {
    float s = f.bq_n1[t];
    const float4* wr = (const float4*)(f.Wq_n1 + (size_t)t * HID);
    const float4* xx = (const float4*)sm.v.xn;
    #pragma unroll 8
    for (int c = 0; c < HID / 4; ++c) {
      float4 w4 = wr[c], x4 = xx[c];
      s += x4.x * w4.x + x4.y * w4.y + x4.z * w4.z + x4.w * w4.w;
    }
    f.qv[v * HID + t] = s;
  }
}

__launch_bounds__(256)
__global__ void k_post(PArgs f) {
  __shared__ SMu sm;
  const int t = threadIdx.x;
  int bx = blockIdx.x;
  if (f.vonly) { vtail(sm, t, bx, f); return; }
  if (bx >= NN / 64) { vtail(sm, t, bx - NN / 64, f); return; }
  const int m0 = bx * 64;
  stage_A(sm.a.Ah, sm.a.Al, t, f.agg, m0, 1);
  __syncthreads();
  f32x4 acc[2][4] = {};
  mfma_pass(sm.a.Ah, sm.a.Al, t, f.WaF_l, acc);
  const int w = t >> 6, c16 = t & 15, quad = (t & 63) >> 4;
  float g = sigmoid_f(*f.skip_l0), gm1 = 1.0f - g;
  #pragma unroll
  for (int j = 0; j < 2; ++j) {
    const int col = (2 * w + j) * 16 + c16;
    const float bb = f.ba_l0[col];
    #pragma unroll
    for (int s = 0; s < 4; ++s)
      #pragma unroll
      for (int r = 0; r < 4; ++r) {
        int lm = 16 * s + quad * 4 + r;
        float v = acc[j][s][r] + bb;
        f.xop[(size_t)(m0 + lm) * HID + col] = g * v + gm1 * f.xold[(size_t)(m0 + lm) * HID + col];
      }
  }
}

// ================= JK attention + node/graph MLPs =============================================
struct TailW {
  const float *win, *bin, *wout, *bout;
  const float *nw0, *nb0, *nw1, *nb1, *nw2, *nb2, *nw3, *nb3, *nw4, *nb4, *nw5, *nb5, *nw6, *nb6;
  const float *gw0, *gb0, *gw1, *gb1;
};

__launch_bounds__(128)
__global__ void k_final(const float* __restrict__ outsv, TailW tw, float* __restrict__ outp) {
  __shared__ float xs[4][HID], qq[4][HID], kk[4][HID], vv[4][HID], oo[4][HID];
  __shared__ float att[NH][4][4];
  __shared__ float hb[HID], tb[64];
  int b = blockIdx.x, t = threadIdx.x;
  for (int l = 0; l < 4; ++l) xs[l][t] = outsv[(size_t)(l * NV + b) * HID + t];
  __syncthreads();
  for (int l = 0; l < 4; ++l) {
    float sq = tw.bin[t], sk = tw.bin[t + 128], sv = tw.bin[t + 256];
    const float* wq = tw.win + (size_t)t * HID;
    const float* wk = tw.win + (size_t)(t + 128) * HID;
    const float* wv = tw.win + (size_t)(t + 256) * HID;
    for (int c = 0; c < HID; ++c) {
      float x = xs[l][c];
      sq += x * wq[c]; sk += x * wk[c]; sv += x * wv[c];
    }
    qq[l][t] = sq; kk[l][t] = sk; vv[l][t] = sv;
  }
  __syncthreads();
  {
    int h = t >> 4, ql = (t >> 2) & 3, kl = t & 3;
    float s = 0.f;
    #pragma unroll
    for (int d = 0; d < DH; ++d) s += qq[ql][h * DH + d] * kk[kl][h * DH + d];
    att[h][ql][kl] = s * SCALE;
  }
  __syncthreads();
  if (t < 32) {
    int h = t >> 2, ql = t & 3;
    float m = att[h][ql][0];
    for (int k2 = 1; k2 < 4; ++k2) m = fmaxf(m, att[h][ql][k2]);
    float e[4], s = 0.f;
    for (int k2 = 0; k2 < 4; ++k2) { e[k2] = __expf(att[h][ql][k2] - m); s += e[k2]; }
    for (int k2 = 0; k2 < 4; ++k2) att[h][ql][k2] = e[k2] / s;
  }
  __syncthreads();
  {
    int h = t >> 4;
    #pragma unroll
    for (int ql = 0; ql < 4; ++ql) {
      float s = 0.f;
      #pragma unroll
      for (int kl = 0; kl < 4; ++kl) s += att[h][ql][kl] * vv[kl][t];
      oo[ql][t] = s;
    }
  }
  __syncthreads();
  {
    float s = 0.f;
    const float* wr = tw.wout + (size_t)t * HID;
    for (int l = 0; l < 4; ++l) {
      float ss = tw.bout[t];
      for (int c = 0; c < HID; ++c) ss += oo[l][c] * wr[c];
      s += ss;
    }
    hb[t] = s;
  }
  __syncthreads();
  if (t < 64) { float s = tw.nb0[t]; const float* wr = tw.nw0 + t * 128; for (int c = 0; c < 128; ++c) s += hb[c] * wr[c]; tb[t] = gelu_f(s); }
  __syncthreads();
  if (t < 32) { float s = tw.nb1[t]; const float* wr = tw.nw1 + t * 64;  for (int c = 0; c < 64;  ++c) s += tb[c] * wr[c]; hb[t] = gelu_f(s); }
  __syncthreads();
  if (t < 16) { float s = tw.nb2[t]; const float* wr = tw.nw2 + t * 32;  for (int c = 0; c < 32;  ++c) s += hb[c] * wr[c]; tb[t] = gelu_f(s); }
  __syncthreads();
  if (t < 8)  { float s = tw.nb3[t]; const float* wr = tw.nw3 + t * 16;  for (int c = 0; c < 16;  ++c) s += tb[c] * wr[c]; hb[t] = gelu_f(s); }
  __syncthreads();
  if (t < 4)  { float s = tw.nb4[t]; const float* wr = tw.nw4 + t * 8;   for (int c = 0; c < 8;   ++c) s += hb[c] * wr[c]; tb[t] = gelu_f(s); }
  __syncthreads();
  if (t < 2)  { float s = tw.nb5[t]; const float* wr = tw.nw5 + t * 4;   for (int c = 0; c < 4;   ++c) s += tb[c] * wr[c]; hb[t] = gelu_f(s); }
  __syncthreads();
  if (t == 0) {
    float s = hb[0] * tw.nw6[0] + hb[1] * tw.nw6[1] + tw.nb6[0];
    float g0 = gelu_f(s * tw.gw0[0] + tw.gb0[0]);
    float g1 = gelu_f(s * tw.gw0[1] + tw.gb0[1]);
    outp[b] = g0 * tw.gw1[0] + g1 * tw.gw1[1] + tw.gb1[0];
  }
}

// ================= host =======================================================================
extern "C" void kernel_launch(void* const* d_in, const int* in_sizes, int n_in,
                              void* d_out, int out_size, void* d_ws, size_t ws_size,
                              hipStream_t stream) {
  const float* x_op = (const float*)d_in[0];
  const float* x_v  = (const float*)d_in[1];
  const int*   ei0  = (const int*)d_in[2];
  const int*   ei1  = (const int*)d_in[3];
  const float* Wk   = (const float*)d_in[4];
  const float* Wq   = (const float*)d_in[5];
  const float* Wv   = (const float*)d_in[6];
  const float* Wa   = (const float*)d_in[7];
  const float* bk   = (const float*)d_in[8];
  const float* bq   = (const float*)d_in[9];
  const float* bv   = (const float*)d_in[10];
  const float* ba   = (const float*)d_in[11];
  const float* skip = (const float*)d_in[12];
  const float* a_rel = (const float*)d_in[13];
  const float* m_rel = (const float*)d_in[14];
  const float* p_rel = (const float*)d_in[15];
  (void)in_sizes; (void)n_in; (void)out_size; (void)ws_size;

  char* wsp = (char*)d_ws;
  size_t off = 0;
  auto alloc = [&](size_t bytes) -> void* {
    void* p = wsp + off;
    off += (bytes + 255) & ~(size_t)255;
    return p;
  };
  float* Pq    = (float*)alloc((size_t)NN * HID * 4);
  unsigned int* Pkv0 = (unsigned int*)alloc((size_t)NN * HID * 4);  // fp16 k|v packed per dword
  unsigned int* Pkv1 = (unsigned int*)alloc((size_t)NN * HID * 4);
  float* xop   = (float*)alloc((size_t)NN * HID * 4);
  float* agg   = (float*)alloc((size_t)NN * HID * 4);
  float* CW    = (float*)alloc((size_t)16 * HID * HID * 4);
  float* CB    = (float*)alloc((size_t)16 * HID * 4);
  unsigned short* FW = (unsigned short*)alloc((size_t)24 * 32768 * 2);  // 1.57 MB frag weights
  float* xv    = (float*)alloc((size_t)NV * HID * 4);
  float* qv    = (float*)alloc((size_t)NV * HID * 4);
  float* outsv = (float*)alloc((size_t)NL * NV * HID * 4);
  float* part  = (float*)alloc((size_t)NV * 32 * 192 * 4);
  int* cnt0    = (int*)alloc((size_t)NN * 4);
  int* colB0   = (int*)alloc((size_t)NN * CAP0 * 4);
  int* cnt1    = (int*)alloc((size_t)NV * 4);
  int* colB1   = (int*)alloc((size_t)NV * CAP1 * 4);

  hipMemsetAsync(cnt0, 0, (size_t)NN * 4, stream);
  hipMemsetAsync(cnt1, 0, (size_t)NV * 4, stream);

  k_setup<<<16, 256, 0, stream>>>(Wk, Wv, bk, bv, a_rel, m_rel, p_rel, CW, CB);
  k_frag<<<24, 256, 0, stream>>>(CW, Wq, Wa, FW);

  PreArgs pa;
  pa.src0 = ei0; pa.dst0 = ei0 + E0E;
  pa.src1 = ei1; pa.dst1 = ei1 + NN;
  pa.cnt0 = cnt0; pa.cnt1 = cnt1; pa.colB0 = colB0; pa.colB1 = colB1;
  pa.x_op = x_op; pa.FW = FW; pa.bq = bq; pa.CB = CB;
  pa.Pq = Pq; pa.Pkv0 = Pkv0; pa.Pkv1 = Pkv1;
  pa.x_v = x_v; pa.Wq1 = Wq + (size_t)1 * HID * HID; pa.bq1 = bq + HID; pa.qv = qv;
  k_pre<<<E0E / 1024 + NN / 1024 + 5 * (NN / 128) + NV, 256, 0, stream>>>(pa);

  for (int l = 0; l < NL; ++l) {
    int e0b = (l < NL - 1) ? NN / 4 : 0;       // l=3 edge0 aggregation is DEAD (x_op unused)
    k_edges<<<e0b + NV * 8, 256, 0, stream>>>(Pq, Pkv0, Pkv1, cnt0, colB0, agg,
                                              qv, cnt1, colB1, part, e0b);
    PArgs f;
    f.agg = agg;
    f.WaF_l = FW + (size_t)(20 + l) * 32768;
    f.ba_l0 = ba + (l * 2 + 0) * HID;
    f.skip_l0 = skip + l * 2 + 0;
    f.xold = (l == 0) ? x_op : xop;
    f.xop = xop;
    f.part = part;
    f.Wa_l1 = Wa + (size_t)(l * 2 + 1) * HID * HID;
    f.ba_l1 = ba + (l * 2 + 1) * HID;
    f.skip_l1 = skip + l * 2 + 1;
    f.xvold = (l == 0) ? x_v : xv;
    f.xv = xv;
    f.outsv_l = outsv + (size_t)l * NV * HID;
    f.qv = qv;
    int ln = (l + 1) & 3;
    f.Wq_n1 = Wq + (size_t)(ln * 2 + 1) * HID * HID;
    f.bq_n1 = bq + (ln * 2 + 1) * HID;
    f.do_qv = (l < NL - 1) ? 1 : 0;
    f.vonly = (l == NL - 1) ? 1 : 0;
    k_post<<<(l < NL - 1) ? (NN / 64 + NV) : NV, 256, 0, stream>>>(f);
    if (l < NL - 1) {
      int ntb = (ln < 3) ? 0 : 3;              // l=2 proj: only K1,V1 survive pruning
      int ntn = (ln < 3) ? 5 : 2;
      k_gproj<<<(NN / 128) * ntn, 256, 0, stream>>>(xop, FW, bq + (size_t)ln * 2 * HID,
                                                    CB + (size_t)ln * 4 * HID,
                                                    Pq, Pkv0, Pkv1, ln, ntb, ntn);
    }
  }

  TailW tw;
  tw.win  = (const float*)d_in[16]; tw.bin  = (const float*)d_in[17];
  tw.wout = (const float*)d_in[18]; tw.bout = (const float*)d_in[19];
  tw.nw0 = (const float*)d_in[20]; tw.nb0 = (const float*)d_in[21];
  tw.nw1 = (const float*)d_in[22]; tw.nb1 = (const float*)d_in[23];
  tw.nw2 = (const float*)d_in[24]; tw.nb2 = (const float*)d_in[25];
  tw.nw3 = (const float*)d_in[26]; tw.nb3 = (const float*)d_in[27];
  tw.nw4 = (const float*)d_in[28]; tw.nb4 = (const float*)d_in[29];
  tw.nw5 = (const float*)d_in[30]; tw.nb5 = (const float*)d_in[31];
  tw.nw6 = (const float*)d_in[32]; tw.nb6 = (const float*)d_in[33];
  tw.gw0 = (const float*)d_in[34]; tw.gb0 = (const float*)d_in[35];
  tw.gw1 = (const float*)d_in[36]; tw.gb1 = (const float*)d_in[37];
  k_final<<<NV, 128, 0, stream>>>(outsv, tw, (float*)d_out);
}

// Round 10
// 628.260 us; speedup vs baseline: 1.2049x; 1.2049x over previous
//
#include <hip/hip_runtime.h>

#define NN   32768
#define NV   64
#define E0E  524288
#define HID  128
#define NL   4
#define NH   8
#define DH   16
#define SCALE 0.25f
#define LDA  136   // bf16 row stride for staged A (16B frag reads, 2-way alias)
#define CAP0 64
#define CAP1 1024

typedef __attribute__((ext_vector_type(8))) short short8;   // 8 bf16 = 4 VGPRs
typedef __attribute__((ext_vector_type(4))) float f32x4;

__device__ __forceinline__ float gelu_f(float x) {
  return 0.5f * x * (1.0f + erff(x * 0.7071067811865475f));
}
__device__ __forceinline__ float sigmoid_f(float x) {
  return 1.0f / (1.0f + __expf(-x));
}
__device__ __forceinline__ unsigned short f2bf(float x) {   // RN-even f32->bf16
  unsigned u = __float_as_uint(x);
  return (unsigned short)((u + 0x7FFFu + ((u >> 16) & 1u)) >> 16);
}
__device__ __forceinline__ float bf2f(unsigned short h) {
  return __uint_as_float(((unsigned)h) << 16);
}
__device__ __forceinline__ unsigned short f2h(float x) {
  union { _Float16 h; unsigned short u; } cv;
  cv.h = (_Float16)x;
  return cv.u;
}
__device__ __forceinline__ float h2f(unsigned short u) {
  union { _Float16 h; unsigned short u; } cv;
  cv.u = u;
  return (float)cv.h;
}
__device__ __forceinline__ float f16lo(unsigned u) { return h2f((unsigned short)(u & 0xffffu)); }
__device__ __forceinline__ float f16hi(unsigned u) { return h2f((unsigned short)(u >> 16)); }

union SMu {
  struct { unsigned short Ah[64][LDA]; unsigned short Al[64][LDA]; } a;  // 34816 B
  struct { float xr[HID]; float xn[HID]; } v;
};

// ---- stage 64xK=128 fp32 tile into split hi/lo bf16 LDS (coalesced float4 reads) ----
__device__ __forceinline__ void stage_A(unsigned short Ah[][LDA], unsigned short Al[][LDA],
                                        int t, const float* __restrict__ A, int m0, int gelu) {
  #pragma unroll
  for (int i = 0; i < 8; ++i) {
    int idx = t + 256 * i;            // float4 index over 64x32
    int m = idx >> 5, c4 = (idx & 31) * 4;
    float4 v = *(const float4*)(A + (size_t)(m0 + m) * HID + c4);
    if (gelu) { v.x = gelu_f(v.x); v.y = gelu_f(v.y); v.z = gelu_f(v.z); v.w = gelu_f(v.w); }
    unsigned short h0 = f2bf(v.x), h1 = f2bf(v.y), h2 = f2bf(v.z), h3 = f2bf(v.w);
    *(ushort4*)&Ah[m][c4] = make_ushort4(h0, h1, h2, h3);
    *(ushort4*)&Al[m][c4] = make_ushort4(f2bf(v.x - bf2f(h0)), f2bf(v.y - bf2f(h1)),
                                         f2bf(v.z - bf2f(h2)), f2bf(v.w - bf2f(h3)));
  }
}

// ---- MFMA split-bf16 single pass: 64x128 tile, K=128, B-reuse form (96 MFMAs/wave) ----
__device__ __forceinline__ void mfma_pass(const unsigned short Ah[][LDA],
    const unsigned short Al[][LDA], int t, const unsigned short* __restrict__ Wf,
    f32x4 acc[2][4]) {
  const int w = t >> 6, lane = t & 63, c16 = lane & 15, quad = lane >> 4;
  #pragma unroll
  for (int ks = 0; ks < 4; ++ks) {
    short8 ah[4], al[4];
    #pragma unroll
    for (int s = 0; s < 4; ++s) {
      ah[s] = *(const short8*)&Ah[16 * s + c16][ks * 32 + quad * 8];
      al[s] = *(const short8*)&Al[16 * s + c16][ks * 32 + quad * 8];
    }
    #pragma unroll
    for (int j = 0; j < 2; ++j) {
      const unsigned short* bp = Wf + (size_t)(((2 * w + j) * 4 + ks) * 64 + lane) * 8;
      short8 bh = *(const short8*)bp;
      short8 bl = *(const short8*)(bp + 16384);
      #pragma unroll
      for (int s = 0; s < 4; ++s) {
        acc[j][s] = __builtin_amdgcn_mfma_f32_16x16x32_bf16(ah[s], bh, acc[j][s], 0, 0, 0);
        acc[j][s] = __builtin_amdgcn_mfma_f32_16x16x32_bf16(ah[s], bl, acc[j][s], 0, 0, 0);
        acc[j][s] = __builtin_amdgcn_mfma_f32_16x16x32_bf16(al[s], bh, acc[j][s], 0, 0, 0);
      }
    }
  }
}

// ---- q slice: 1 pass + fp32 write ----
__device__ __forceinline__ void proj_q(const unsigned short Ah[][LDA],
    const unsigned short Al[][LDA], int t, int m0,
    const unsigned short* __restrict__ WqF, const float* __restrict__ bq0,
    float* __restrict__ Pq) {
  const int w = t >> 6, c16 = t & 15, quad = (t & 63) >> 4;
  f32x4 acc[2][4] = {};
  mfma_pass(Ah, Al, t, WqF, acc);
  #pragma unroll
  for (int j = 0; j < 2; ++j) {
    const int col = (2 * w + j) * 16 + c16;
    const float bb = bq0[col];
    #pragma unroll
    for (int s = 0; s < 4; ++s)
      #pragma unroll
      for (int r = 0; r < 4; ++r) {
        int m = m0 + 16 * s + quad * 4 + r;
        Pq[(size_t)m * HID + col] = acc[j][s][r] + bb;
      }
  }
}

// ---- k|v slice: K pass (packed to 16 u32) then V pass, full-dword fp16 pair write ----
// (r8 lesson: 2-byte half-stores from separate blocks double HBM writeback; keep dword writes.)
__device__ __forceinline__ void proj_kv(const unsigned short Ah[][LDA],
    const unsigned short Al[][LDA], int t, int m0,
    const unsigned short* __restrict__ WfK, const float* __restrict__ bK,
    const float* __restrict__ bV, unsigned int* __restrict__ dst) {
  const int w = t >> 6, c16 = t & 15, quad = (t & 63) >> 4;
  unsigned kp[2][4][2];
  {
    f32x4 accK[2][4] = {};
    mfma_pass(Ah, Al, t, WfK, accK);
    #pragma unroll
    for (int j = 0; j < 2; ++j) {
      const float bbk = bK[(2 * w + j) * 16 + c16];
      #pragma unroll
      for (int s = 0; s < 4; ++s)
        #pragma unroll
        for (int rr = 0; rr < 2; ++rr)
          kp[j][s][rr] = (unsigned)f2h(accK[j][s][2 * rr] + bbk)
                       | ((unsigned)f2h(accK[j][s][2 * rr + 1] + bbk) << 16);
    }
  }
  f32x4 accV[2][4] = {};
  mfma_pass(Ah, Al, t, WfK + 32768, accV);
  #pragma unroll
  for (int j = 0; j < 2; ++j) {
    const int col = (2 * w + j) * 16 + c16;
    const float bbv = bV[col];
    #pragma unroll
    for (int s = 0; s < 4; ++s)
      #pragma unroll
      for (int r = 0; r < 4; ++r) {
        int m = m0 + 16 * s + quad * 4 + r;
        unsigned pk = (kp[j][s][r >> 1] >> ((r & 1) * 16)) & 0xffffu;
        unsigned pv = (unsigned)f2h(accV[j][s][r] + bbv);
        dst[(size_t)m * HID + col] = pk | (pv << 16);
      }
  }
}

// ================= k_setup: weight-combine only (16 blocks) ===================================
__global__ __launch_bounds__(256) void k_setup(
    const float* __restrict__ Wk, const float* __restrict__ Wv,
    const float* __restrict__ bk, const float* __restrict__ bv,
    const float* __restrict__ a_rel, const float* __restrict__ m_rel,
    const float* __restrict__ p_rel,
    float* __restrict__ CW, float* __restrict__ CB) {
  int blk = blockIdx.x, t = threadIdx.x;   // 0..15: l*4 + {K0,V0,K1,V1}
  int l = blk >> 2, mat = blk & 3;
  int rel = mat >> 1;
  int isK = ((mat & 1) == 0);
  const float* W  = (isK ? Wk : Wv) + (size_t)(l * 2) * HID * HID;
  const float* bb = (isK ? bk : bv) + (l * 2) * HID;
  const float* R  = (isK ? a_rel : m_rel) + (size_t)((l * 2 + rel) * NH) * DH * DH;
  float* cw = CW + (size_t)blk * HID * HID;
  float* cb = CB + blk * HID;
  for (int o = t; o < HID * HID; o += 256) {
    int j = o >> 7, c = o & 127;
    int h = j >> 4, e = j & 15;
    float sc = isK ? (p_rel[(l * 2 + rel) * NH + h] * SCALE) : 1.0f;
    float s = 0.f;
    #pragma unroll
    for (int d = 0; d < DH; ++d)
      s += W[(size_t)(h * DH + d) * HID + c] * R[h * 256 + d * 16 + e];
    cw[(size_t)j * HID + c] = s * sc;   // [n][k]
  }
  if (t < HID) {
    int j = t, h = j >> 4, e = j & 15;
    float sc = isK ? (p_rel[(l * 2 + rel) * NH + h] * SCALE) : 1.0f;
    float s = 0.f;
    #pragma unroll
    for (int d = 0; d < DH; ++d) s += bb[h * DH + d] * R[h * 256 + d * 16 + e];
    cb[j] = s * sc;
  }
}

// ================= frag-order + split all 24 weight mats (CW 0-15, Wq0 16-19, Wa0 20-23) ======
__global__ __launch_bounds__(256) void k_frag(const float* __restrict__ CW,
                                              const float* __restrict__ Wq,
                                              const float* __restrict__ Wa,
                                              unsigned short* __restrict__ FW) {
  int m = blockIdx.x, t = threadIdx.x;
  const float* src = (m < 16) ? (CW + (size_t)m * HID * HID)
                   : (m < 20) ? (Wq + (size_t)((m - 16) * 2) * HID * HID)
                              : (Wa + (size_t)((m - 20) * 2) * HID * HID);
  unsigned short* hi = FW + (size_t)m * 32768;
  unsigned short* lo = hi + 16384;
  for (int idx = t; idx < 16384; idx += 256) {
    int j = idx & 7, lane = (idx >> 3) & 63, ks = (idx >> 9) & 3, nt = idx >> 11;
    int n = nt * 16 + (lane & 15);
    int k = ks * 32 + (lane >> 4) * 8 + j;
    float x = src[(size_t)n * HID + k];
    unsigned short h = f2bf(x);
    hi[idx] = h;
    lo[idx] = f2bf(x - bf2f(h));
  }
}

// ================= k_pre: bucket-scatter (4/thr) + layer-0 proj (y-sliced, 3 blk/tile) + qv0 ==
// 34KB LDS only (r8 lesson: a 67.5KB plane caps the WHOLE fused kernel at 2 blk/CU and
// starves the scatter). Slice redundancy here is just stage_A re-reads (L3-hot x_op).
struct PreArgs {
  const int *src0, *dst0, *src1, *dst1;
  int *cnt0, *cnt1, *colB0, *colB1;
  const float* x_op; const unsigned short* FW; const float *bq, *CB;
  float* Pq; unsigned int *Pkv0, *Pkv1;
  const float *x_v, *Wq1, *bq1; float* qv;
};

__launch_bounds__(256)
__global__ void k_pre(PreArgs a) {
  __shared__ SMu sm;
  int bx = blockIdx.x, t = threadIdx.x;
  if (bx < E0E / 1024) {                     // edge0 bucket scatter (4 edges/thread ILP)
    int base = bx * 1024 + t;
    #pragma unroll
    for (int i = 0; i < 4; ++i) {
      int e = base + i * 256;
      int d = a.dst0[e];
      int pos = atomicAdd(&a.cnt0[d], 1);
      if (pos < CAP0) a.colB0[((size_t)d << 6) + pos] = a.src0[e];
    }
    return;
  }
  bx -= E0E / 1024;
  if (bx < NN / 1024) {                      // edge1 bucket scatter
    int base = bx * 1024 + t;
    #pragma unroll
    for (int i = 0; i < 4; ++i) {
      int e = base + i * 256;
      int d = a.dst1[e];
      int pos = atomicAdd(&a.cnt1[d], 1);
      if (pos < CAP1) a.colB1[((size_t)d << 10) + pos] = a.src1[e];
    }
    return;
  }
  bx -= NN / 1024;
  if (bx < 3 * (NN / 64)) {                  // layer-0 projection slice: tile | slice y
    int y = bx >> 9, tile = bx & 511;
    int m0 = tile * 64;
    stage_A(sm.a.Ah, sm.a.Al, t, a.x_op, m0, 0);
    __syncthreads();
    if (y == 0)      proj_q (sm.a.Ah, sm.a.Al, t, m0, a.FW + (size_t)16 * 32768, a.bq, a.Pq);
    else if (y == 1) proj_kv(sm.a.Ah, sm.a.Al, t, m0, a.FW, a.CB, a.CB + HID, a.Pkv0);
    else             proj_kv(sm.a.Ah, sm.a.Al, t, m0, a.FW + (size_t)2 * 32768,
                             a.CB + 2 * HID, a.CB + 3 * HID, a.Pkv1);
    return;
  }
  bx -= 3 * (NN / 64);                       // qv0 for vnode bx
  if (t < HID) sm.v.xr[t] = a.x_v[bx * HID + t];
  __syncthreads();
  if (t < HID) {
    float s = a.bq1[t];
    const float4* wr = (const float4*)(a.Wq1 + (size_t)t * HID);
    const float4* xx = (const float4*)sm.v.xr;
    #pragma unroll 8
    for (int c = 0; c < HID / 4; ++c) {
      float4 w4 = wr[c], x4 = xx[c];
      s += x4.x * w4.x + x4.y * w4.y + x4.z * w4.z + x4.w * w4.w;
    }
    a.qv[bx * HID + t] = s;
  }
}

// ================= k_edges: edge0 (blocks < e0blocks; DEAD at l=3) + edge1 =====================
__launch_bounds__(256)
__global__ void k_edges(const float* __restrict__ Pq, const unsigned int* __restrict__ Pkv0,
                        const unsigned int* __restrict__ Pkv1,
                        const int* __restrict__ cnt0, const int* __restrict__ colB0,
                        float* __restrict__ agg, const float* __restrict__ qv,
                        const int* __restrict__ cnt1, const int* __restrict__ colB1,
                        float* __restrict__ part, int e0blocks) {
  int lane = threadIdx.x & 63;
  if (blockIdx.x < e0blocks) {
    int n = blockIdx.x * 4 + (threadIdx.x >> 6);
    float2 q = *(const float2*)(Pq + (size_t)n * HID + 2 * lane);
    int cnt = cnt0[n]; if (cnt > CAP0) cnt = CAP0;
    int e = n << 6, e1 = (n << 6) + cnt;
    float acc0 = 0.f, acc1 = 0.f, wsum = 0.f;
    for (; e + 8 <= e1; e += 8) {
      const uint2* r[8];
      #pragma unroll
      for (int u = 0; u < 8; ++u)
        r[u] = (const uint2*)(Pkv0 + ((size_t)colB0[e + u] << 7) + 2 * lane);
      uint2 kv[8];
      #pragma unroll
      for (int u = 0; u < 8; ++u) kv[u] = *r[u];
      float p[8];
      #pragma unroll
      for (int u = 0; u < 8; ++u)
        p[u] = q.x * f16lo(kv[u].x) + q.y * f16lo(kv[u].y);
      #pragma unroll
      for (int u = 0; u < 8; ++u) {
        p[u] += __shfl_xor(p[u], 1); p[u] += __shfl_xor(p[u], 2); p[u] += __shfl_xor(p[u], 4);
      }
      #pragma unroll
      for (int u = 0; u < 8; ++u) {
        float wg = __expf(p[u]);
        wsum += wg; acc0 += wg * f16hi(kv[u].x); acc1 += wg * f16hi(kv[u].y);
      }
    }
    for (; e < e1; ++e) {
      uint2 kv = *(const uint2*)(Pkv0 + ((size_t)colB0[e] << 7) + 2 * lane);
      float p = q.x * f16lo(kv.x) + q.y * f16lo(kv.y);
      p += __shfl_xor(p, 1); p += __shfl_xor(p, 2); p += __shfl_xor(p, 4);
      float wg = __expf(p);
      wsum += wg; acc0 += wg * f16hi(kv.x); acc1 += wg * f16hi(kv.y);
    }
    float inv = 1.0f / (wsum + 1e-16f);
    *(float2*)(agg + (size_t)n * HID + 2 * lane) = make_float2(acc0 * inv, acc1 * inv);
  } else {
    int b2 = blockIdx.x - e0blocks;
    int g = b2 >> 3, ch = b2 & 7;
    int w = threadIdx.x >> 6;
    int slot = ch * 4 + w;
    float2 q = *(const float2*)(qv + g * HID + 2 * lane);
    int tot = cnt1[g]; if (tot > CAP1) tot = CAP1;
    int base = g << 10;
    int len = (tot + 31) >> 5;
    int s0 = base + slot * len;
    int s1 = s0 + len; int lim = base + tot; if (s1 > lim) s1 = lim;
    float acc0 = 0.f, acc1 = 0.f, wsum = 0.f;
    int e = s0;
    for (; e + 4 <= s1; e += 4) {
      uint2 ka = *(const uint2*)(Pkv1 + ((size_t)colB1[e]     << 7) + 2 * lane);
      uint2 kb = *(const uint2*)(Pkv1 + ((size_t)colB1[e + 1] << 7) + 2 * lane);
      uint2 kc = *(const uint2*)(Pkv1 + ((size_t)colB1[e + 2] << 7) + 2 * lane);
      uint2 kd = *(const uint2*)(Pkv1 + ((size_t)colB1[e + 3] << 7) + 2 * lane);
      float pa = q.x * f16lo(ka.x) + q.y * f16lo(ka.y);
      float pb = q.x * f16lo(kb.x) + q.y * f16lo(kb.y);
      float pc = q.x * f16lo(kc.x) + q.y * f16lo(kc.y);
      float pd = q.x * f16lo(kd.x) + q.y * f16lo(kd.y);
      pa += __shfl_xor(pa, 1); pb += __shfl_xor(pb, 1); pc += __shfl_xor(pc, 1); pd += __shfl_xor(pd, 1);
      pa += __shfl_xor(pa, 2); pb += __shfl_xor(pb, 2); pc += __shfl_xor(pc, 2); pd += __shfl_xor(pd, 2);
      pa += __shfl_xor(pa, 4); pb += __shfl_xor(pb, 4); pc += __shfl_xor(pc, 4); pd += __shfl_xor(pd, 4);
      float wa = __expf(pa), wb = __expf(pb), wc = __expf(pc), wd = __expf(pd);
      wsum += (wa + wb) + (wc + wd);
      acc0 += wa * f16hi(ka.x) + wb * f16hi(kb.x) + wc * f16hi(kc.x) + wd * f16hi(kd.x);
      acc1 += wa * f16hi(ka.y) + wb * f16hi(kb.y) + wc * f16hi(kc.y) + wd * f16hi(kd.y);
    }
    for (; e < s1; ++e) {
      uint2 kv = *(const uint2*)(Pkv1 + ((size_t)colB1[e] << 7) + 2 * lane);
      float p = q.x * f16lo(kv.x) + q.y * f16lo(kv.y);
      p += __shfl_xor(p, 1); p += __shfl_xor(p, 2); p += __shfl_xor(p, 4);
      float ww = __expf(p);
      wsum += ww; acc0 += ww * f16hi(kv.x); acc1 += ww * f16hi(kv.y);
    }
    float* pp = part + (size_t)(g * 32 + slot) * 192;
    pp[lane] = acc0; pp[64 + lane] = acc1; pp[128 + lane] = wsum;
  }
}

// ================= k_post: fused post-GEMM + next-layer proj (r6 form, races-free) =============
// mode 0 (l=0,1): post (+xop write) + restage + proj q,kv0,kv1 (serial, no redundancy).
// mode 1 (l=2):   post (xop DEAD -> no write) + restage + proj kv1 only (Pq/Pkv0 dead).
// mode 2 (l=3):   vnode tail only.
struct PArgs {
  const float *agg; const unsigned short *WaF_l; const float *ba_l0, *skip_l0, *xold;
  float *xop;
  const float *part, *Wa_l1, *ba_l1, *skip_l1, *xvold;
  float *xv, *outsv_l, *qv;
  const float *Wq_n1, *bq_n1;
  int do_qv;
  const unsigned short *WqF_n, *CWF_n;   // next-layer frag weights
  const float *bq_n0, *CB_n;
  float *Pq; unsigned int *Pkv0, *Pkv1;
  int mode;
};

__device__ __forceinline__ void vtail(SMu& sm, int t, int v, const PArgs& f) {
  if (t < 64) {
    float a0 = 0.f, a1 = 0.f, ws2 = 0.f;
    for (int s = 0; s < 32; ++s) {
      const float* p = f.part + (size_t)(v * 32 + s) * 192;
      a0 += p[t]; a1 += p[64 + t]; ws2 += p[128 + t];
    }
    float inv = 1.0f / (ws2 + 1e-16f);
    sm.v.xr[2 * t]     = gelu_f(a0 * inv);
    sm.v.xr[2 * t + 1] = gelu_f(a1 * inv);
  }
  __syncthreads();
  if (t < HID) {
    float s = f.ba_l1[t];
    const float4* wr = (const float4*)(f.Wa_l1 + (size_t)t * HID);
    const float4* xx = (const float4*)sm.v.xr;
    #pragma unroll 8
    for (int c = 0; c < HID / 4; ++c) {
      float4 w4 = wr[c], x4 = xx[c];
      s += x4.x * w4.x + x4.y * w4.y + x4.z * w4.z + x4.w * w4.w;
    }
    float gg = sigmoid_f(*f.skip_l1);
    float nv2 = gg * s + (1.f - gg) * f.xvold[v * HID + t];
    f.xv[v * HID + t] = nv2;
    f.outsv_l[v * HID + t] = nv2;
    sm.v.xn[t] = nv2;
  }
  __syncthreads();
  if (f.do_qv && t < HID) {
    float s = f.bq_n1[t];
    const float4* wr = (const float4*)(f.Wq_n1 + (size_t)t * HID);
    const float4* xx = (const float4*)sm.v.xn;
    #pragma unroll 8
    for (int c = 0; c < HID / 4; ++c) {
      float4 w4 = wr[c], x4 = xx[c];
      s += x4.x * w4.x + x4.y * w4.y + x4.z * w4.z + x4.w * w4.w;
    }
    f.qv[v * HID + t] = s;
  }
}

__launch_bounds__(256)
__global__ void k_post(PArgs f) {
  __shared__ SMu sm;
  const int t = threadIdx.x;
  int bx = blockIdx.x;
  if (f.mode == 2) { vtail(sm, t, bx, f); return; }
  if (bx >= NN / 64) { vtail(sm, t, bx - NN / 64, f); return; }
  const int m0 = bx * 64;
  stage_A(sm.a.Ah, sm.a.Al, t, f.agg, m0, 1);
  __syncthreads();
  f32x4 acc[2][4] = {};
  mfma_pass(sm.a.Ah, sm.a.Al, t, f.WaF_l, acc);
  const int w = t >> 6, c16 = t & 15, quad = (t & 63) >> 4;
  float g = sigmoid_f(*f.skip_l0), gm1 = 1.0f - g;
  #pragma unroll
  for (int j = 0; j < 2; ++j) {
    const int col = (2 * w + j) * 16 + c16;
    const float bb = f.ba_l0[col];
    #pragma unroll
    for (int s = 0; s < 4; ++s)
      #pragma unroll
      for (int r = 0; r < 4; ++r) {
        int lm = 16 * s + quad * 4 + r;
        float v = acc[j][s][r] + bb;
        v = g * v + gm1 * f.xold[(size_t)(m0 + lm) * HID + col];
        acc[j][s][r] = v;                         // keep for re-stage
        if (f.mode == 0)
          f.xop[(size_t)(m0 + lm) * HID + col] = v;
      }
  }
  __syncthreads();                                // all waves done reading old A tile
  #pragma unroll
  for (int j = 0; j < 2; ++j) {
    const int col = (2 * w + j) * 16 + c16;
    #pragma unroll
    for (int s = 0; s < 4; ++s)
      #pragma unroll
      for (int r = 0; r < 4; ++r) {
        int lm = 16 * s + quad * 4 + r;
        float v = acc[j][s][r];
        unsigned short h = f2bf(v);
        sm.a.Ah[lm][col] = h;
        sm.a.Al[lm][col] = f2bf(v - bf2f(h));
      }
  }
  __syncthreads();
  if (f.mode == 1) {                              // l=2: only rel1 k|v survives pruning
    proj_kv(sm.a.Ah, sm.a.Al, t, m0, f.CWF_n + (size_t)2 * 32768,
            f.CB_n + 2 * HID, f.CB_n + 3 * HID, f.Pkv1);
    return;
  }
  proj_q (sm.a.Ah, sm.a.Al, t, m0, f.WqF_n, f.bq_n0, f.Pq);
  proj_kv(sm.a.Ah, sm.a.Al, t, m0, f.CWF_n, f.CB_n, f.CB_n + HID, f.Pkv0);
  proj_kv(sm.a.Ah, sm.a.Al, t, m0, f.CWF_n + (size_t)2 * 32768,
          f.CB_n + 2 * HID, f.CB_n + 3 * HID, f.Pkv1);
}

// ================= JK attention + node/graph MLPs =============================================
struct TailW {
  const float *win, *bin, *wout, *bout;
  const float *nw0, *nb0, *nw1, *nb1, *nw2, *nb2, *nw3, *nb3, *nw4, *nb4, *nw5, *nb5, *nw6, *nb6;
  const float *gw0, *gb0, *gw1, *gb1;
};

__launch_bounds__(128)
__global__ void k_final(const float* __restrict__ outsv, TailW tw, float* __restrict__ outp) {
  __shared__ float xs[4][HID], qq[4][HID], kk[4][HID], vv[4][HID], oo[4][HID];
  __shared__ float att[NH][4][4];
  __shared__ float hb[HID], tb[64];
  int b = blockIdx.x, t = threadIdx.x;
  for (int l = 0; l < 4; ++l) xs[l][t] = outsv[(size_t)(l * NV + b) * HID + t];
  __syncthreads();
  for (int l = 0; l < 4; ++l) {
    float sq = tw.bin[t], sk = tw.bin[t + 128], sv = tw.bin[t + 256];
    const float* wq = tw.win + (size_t)t * HID;
    const float* wk = tw.win + (size_t)(t + 128) * HID;
    const float* wv = tw.win + (size_t)(t + 256) * HID;
    for (int c = 0; c < HID; ++c) {
      float x = xs[l][c];
      sq += x * wq[c]; sk += x * wk[c]; sv += x * wv[c];
    }
    qq[l][t] = sq; kk[l][t] = sk; vv[l][t] = sv;
  }
  __syncthreads();
  {
    int h = t >> 4, ql = (t >> 2) & 3, kl = t & 3;
    float s = 0.f;
    #pragma unroll
    for (int d = 0; d < DH; ++d) s += qq[ql][h * DH + d] * kk[kl][h * DH + d];
    att[h][ql][kl] = s * SCALE;
  }
  __syncthreads();
  if (t < 32) {
    int h = t >> 2, ql = t & 3;
    float m = att[h][ql][0];
    for (int k2 = 1; k2 < 4; ++k2) m = fmaxf(m, att[h][ql][k2]);
    float e[4], s = 0.f;
    for (int k2 = 0; k2 < 4; ++k2) { e[k2] = __expf(att[h][ql][k2] - m); s += e[k2]; }
    for (int k2 = 0; k2 < 4; ++k2) att[h][ql][k2] = e[k2] / s;
  }
  __syncthreads();
  {
    int h = t >> 4;
    #pragma unroll
    for (int ql = 0; ql < 4; ++ql) {
      float s = 0.f;
      #pragma unroll
      for (int kl = 0; kl < 4; ++kl) s += att[h][ql][kl] * vv[kl][t];
      oo[ql][t] = s;
    }
  }
  __syncthreads();
  {
    float s = 0.f;
    const float* wr = tw.wout + (size_t)t * HID;
    for (int l = 0; l < 4; ++l) {
      float ss = tw.bout[t];
      for (int c = 0; c < HID; ++c) ss += oo[l][c] * wr[c];
      s += ss;
    }
    hb[t] = s;
  }
  __syncthreads();
  if (t < 64) { float s = tw.nb0[t]; const float* wr = tw.nw0 + t * 128; for (int c = 0; c < 128; ++c) s += hb[c] * wr[c]; tb[t] = gelu_f(s); }
  __syncthreads();
  if (t < 32) { float s = tw.nb1[t]; const float* wr = tw.nw1 + t * 64;  for (int c = 0; c < 64;  ++c) s += tb[c] * wr[c]; hb[t] = gelu_f(s); }
  __syncthreads();
  if (t < 16) { float s = tw.nb2[t]; const float* wr = tw.nw2 + t * 32;  for (int c = 0; c < 32;  ++c) s += hb[c] * wr[c]; tb[t] = gelu_f(s); }
  __syncthreads();
  if (t < 8)  { float s = tw.nb3[t]; const float* wr = tw.nw3 + t * 16;  for (int c = 0; c < 16;  ++c) s += tb[c] * wr[c]; hb[t] = gelu_f(s); }
  __syncthreads();
  if (t < 4)  { float s = tw.nb4[t]; const float* wr = tw.nw4 + t * 8;   for (int c = 0; c < 8;   ++c) s += hb[c] * wr[c]; tb[t] = gelu_f(s); }
  __syncthreads();
  if (t < 2)  { float s = tw.nb5[t]; const float* wr = tw.nw5 + t * 4;   for (int c = 0; c < 4;   ++c) s += tb[c] * wr[c]; hb[t] = gelu_f(s); }
  __syncthreads();
  if (t == 0) {
    float s = hb[0] * tw.nw6[0] + hb[1] * tw.nw6[1] + tw.nb6[0];
    float g0 = gelu_f(s * tw.gw0[0] + tw.gb0[0]);
    float g1 = gelu_f(s * tw.gw0[1] + tw.gb0[1]);
    outp[b] = g0 * tw.gw1[0] + g1 * tw.gw1[1] + tw.gb1[0];
  }
}

// ================= host =======================================================================
extern "C" void kernel_launch(void* const* d_in, const int* in_sizes, int n_in,
                              void* d_out, int out_size, void* d_ws, size_t ws_size,
                              hipStream_t stream) {
  const float* x_op = (const float*)d_in[0];
  const float* x_v  = (const float*)d_in[1];
  const int*   ei0  = (const int*)d_in[2];
  const int*   ei1  = (const int*)d_in[3];
  const float* Wk   = (const float*)d_in[4];
  const float* Wq   = (const float*)d_in[5];
  const float* Wv   = (const float*)d_in[6];
  const float* Wa   = (const float*)d_in[7];
  const float* bk   = (const float*)d_in[8];
  const float* bq   = (const float*)d_in[9];
  const float* bv   = (const float*)d_in[10];
  const float* ba   = (const float*)d_in[11];
  const float* skip = (const float*)d_in[12];
  const float* a_rel = (const float*)d_in[13];
  const float* m_rel = (const float*)d_in[14];
  const float* p_rel = (const float*)d_in[15];
  (void)in_sizes; (void)n_in; (void)out_size; (void)ws_size;

  char* wsp = (char*)d_ws;
  size_t off = 0;
  auto alloc = [&](size_t bytes) -> void* {
    void* p = wsp + off;
    off += (bytes + 255) & ~(size_t)255;
    return p;
  };
  float* Pq    = (float*)alloc((size_t)NN * HID * 4);
  unsigned int* Pkv0 = (unsigned int*)alloc((size_t)NN * HID * 4);  // fp16 k|v packed per dword
  unsigned int* Pkv1 = (unsigned int*)alloc((size_t)NN * HID * 4);
  float* xop   = (float*)alloc((size_t)NN * HID * 4);
  float* agg   = (float*)alloc((size_t)NN * HID * 4);
  float* CW    = (float*)alloc((size_t)16 * HID * HID * 4);
  float* CB    = (float*)alloc((size_t)16 * HID * 4);
  unsigned short* FW = (unsigned short*)alloc((size_t)24 * 32768 * 2);  // 1.57 MB frag weights
  float* xv    = (float*)alloc((size_t)NV * HID * 4);
  float* qv    = (float*)alloc((size_t)NV * HID * 4);
  float* outsv = (float*)alloc((size_t)NL * NV * HID * 4);
  float* part  = (float*)alloc((size_t)NV * 32 * 192 * 4);
  int* cnt0    = (int*)alloc((size_t)NN * 4);
  int* colB0   = (int*)alloc((size_t)NN * CAP0 * 4);
  int* cnt1    = (int*)alloc((size_t)NV * 4);
  int* colB1   = (int*)alloc((size_t)NV * CAP1 * 4);

  hipMemsetAsync(cnt0, 0, (size_t)NN * 4, stream);
  hipMemsetAsync(cnt1, 0, (size_t)NV * 4, stream);

  k_setup<<<16, 256, 0, stream>>>(Wk, Wv, bk, bv, a_rel, m_rel, p_rel, CW, CB);
  k_frag<<<24, 256, 0, stream>>>(CW, Wq, Wa, FW);

  PreArgs pa;
  pa.src0 = ei0; pa.dst0 = ei0 + E0E;
  pa.src1 = ei1; pa.dst1 = ei1 + NN;
  pa.cnt0 = cnt0; pa.cnt1 = cnt1; pa.colB0 = colB0; pa.colB1 = colB1;
  pa.x_op = x_op; pa.FW = FW; pa.bq = bq; pa.CB = CB;
  pa.Pq = Pq; pa.Pkv0 = Pkv0; pa.Pkv1 = Pkv1;
  pa.x_v = x_v; pa.Wq1 = Wq + (size_t)1 * HID * HID; pa.bq1 = bq + HID; pa.qv = qv;
  k_pre<<<E0E / 1024 + NN / 1024 + 3 * (NN / 64) + NV, 256, 0, stream>>>(pa);

  for (int l = 0; l < NL; ++l) {
    int e0b = (l < NL - 1) ? NN / 4 : 0;       // l=3 edge0 aggregation is DEAD (x_op unused)
    k_edges<<<e0b + NV * 8, 256, 0, stream>>>(Pq, Pkv0, Pkv1, cnt0, colB0, agg,
                                              qv, cnt1, colB1, part, e0b);
    PArgs f;
    f.agg = agg;
    f.WaF_l = FW + (size_t)(20 + l) * 32768;
    f.ba_l0 = ba + (l * 2 + 0) * HID;
    f.skip_l0 = skip + l * 2 + 0;
    f.xold = (l == 0) ? x_op : xop;
    f.xop = xop;
    f.part = part;
    f.Wa_l1 = Wa + (size_t)(l * 2 + 1) * HID * HID;
    f.ba_l1 = ba + (l * 2 + 1) * HID;
    f.skip_l1 = skip + l * 2 + 1;
    f.xvold = (l == 0) ? x_v : xv;
    f.xv = xv;
    f.outsv_l = outsv + (size_t)l * NV * HID;
    f.qv = qv;
    int ln = (l + 1) & 3;
    f.Wq_n1 = Wq + (size_t)(ln * 2 + 1) * HID * HID;
    f.bq_n1 = bq + (ln * 2 + 1) * HID;
    f.do_qv = (l < NL - 1) ? 1 : 0;
    f.WqF_n = FW + (size_t)(16 + ln) * 32768;
    f.CWF_n = FW + (size_t)(ln * 4) * 32768;
    f.bq_n0 = bq + (ln * 2 + 0) * HID;
    f.CB_n  = CB + ln * 4 * HID;
    f.Pq = Pq; f.Pkv0 = Pkv0; f.Pkv1 = Pkv1;
    f.mode = (l < 2) ? 0 : (l == 2) ? 1 : 2;
    k_post<<<(l < NL - 1) ? (NN / 64 + NV) : NV, 256, 0, stream>>>(f);
  }

  TailW tw;
  tw.win  = (const float*)d_in[16]; tw.bin  = (const float*)d_in[17];
  tw.wout = (const float*)d_in[18]; tw.bout = (const float*)d_in[19];
  tw.nw0 = (const float*)d_in[20]; tw.nb0 = (const float*)d_in[21];
  tw.nw1 = (const float*)d_in[22]; tw.nb1 = (const float*)d_in[23];
  tw.nw2 = (const float*)d_in[24]; tw.nb2 = (const float*)d_in[25];
  tw.nw3 = (const float*)d_in[26]; tw.nb3 = (const float*)d_in[27];
  tw.nw4 = (const float*)d_in[28]; tw.nb4 = (const float*)d_in[29];
  tw.nw5 = (const float*)d_in[30]; tw.nb5 = (const float*)d_in[31];
  tw.nw6 = (const float*)d_in[32]; tw.nb6 = (const float*)d_in[33];
  tw.gw0 = (const float*)d_in[34]; tw.gb0 = (const float*)d_in[35];
  tw.gw1 = (const float*)d_in[36]; tw.gb1 = (const float*)d_in[37];
  k_final<<<NV, 128, 0, stream>>>(outsv, tw, (float*)d_out);
}

// Round 11
// 560.628 us; speedup vs baseline: 1.3503x; 1.1206x over previous
//
#include <hip/hip_runtime.h>

#define NN   32768
#define NV   64
#define E0E  524288
#define HID  128
#define NL   4
#define NH   8
#define DH   16
#define SCALE 0.25f
#define LDA  136   // bf16 row stride for staged A (16B frag reads, 2-way alias)
#define CAP0 64
#define CAP1 1024

typedef __attribute__((ext_vector_type(8))) short short8;   // 8 bf16 = 4 VGPRs
typedef __attribute__((ext_vector_type(4))) float f32x4;

__device__ __forceinline__ float gelu_f(float x) {
  return 0.5f * x * (1.0f + erff(x * 0.7071067811865475f));
}
__device__ __forceinline__ float sigmoid_f(float x) {
  return 1.0f / (1.0f + __expf(-x));
}
__device__ __forceinline__ unsigned short f2bf(float x) {   // RN-even f32->bf16
  unsigned u = __float_as_uint(x);
  return (unsigned short)((u + 0x7FFFu + ((u >> 16) & 1u)) >> 16);
}
__device__ __forceinline__ float bf2f(unsigned short h) {
  return __uint_as_float(((unsigned)h) << 16);
}
__device__ __forceinline__ unsigned short f2h(float x) {
  union { _Float16 h; unsigned short u; } cv;
  cv.h = (_Float16)x;
  return cv.u;
}
__device__ __forceinline__ float h2f(unsigned short u) {
  union { _Float16 h; unsigned short u; } cv;
  cv.u = u;
  return (float)cv.h;
}
__device__ __forceinline__ float f16lo(unsigned u) { return h2f((unsigned short)(u & 0xffffu)); }
__device__ __forceinline__ float f16hi(unsigned u) { return h2f((unsigned short)(u >> 16)); }

union SMu {
  struct { unsigned short Ah[64][LDA]; unsigned short Al[64][LDA]; } a;  // 34816 B
  struct { float xr[HID]; float xn[HID]; } v;
};

// ---- stage 64xK=128 fp32 tile into split hi/lo bf16 LDS (coalesced float4 reads) ----
__device__ __forceinline__ void stage_A(unsigned short Ah[][LDA], unsigned short Al[][LDA],
                                        int t, const float* __restrict__ A, int m0, int gelu) {
  #pragma unroll
  for (int i = 0; i < 8; ++i) {
    int idx = t + 256 * i;            // float4 index over 64x32
    int m = idx >> 5, c4 = (idx & 31) * 4;
    float4 v = *(const float4*)(A + (size_t)(m0 + m) * HID + c4);
    if (gelu) { v.x = gelu_f(v.x); v.y = gelu_f(v.y); v.z = gelu_f(v.z); v.w = gelu_f(v.w); }
    unsigned short h0 = f2bf(v.x), h1 = f2bf(v.y), h2 = f2bf(v.z), h3 = f2bf(v.w);
    *(ushort4*)&Ah[m][c4] = make_ushort4(h0, h1, h2, h3);
    *(ushort4*)&Al[m][c4] = make_ushort4(f2bf(v.x - bf2f(h0)), f2bf(v.y - bf2f(h1)),
                                         f2bf(v.z - bf2f(h2)), f2bf(v.w - bf2f(h3)));
  }
}

// ---- MFMA split-bf16 single pass: 64x128 tile, K=128, B-reuse form (96 MFMAs/wave) ----
__device__ __forceinline__ void mfma_pass(const unsigned short Ah[][LDA],
    const unsigned short Al[][LDA], int t, const unsigned short* __restrict__ Wf,
    f32x4 acc[2][4]) {
  const int w = t >> 6, lane = t & 63, c16 = lane & 15, quad = lane >> 4;
  #pragma unroll
  for (int ks = 0; ks < 4; ++ks) {
    short8 ah[4], al[4];
    #pragma unroll
    for (int s = 0; s < 4; ++s) {
      ah[s] = *(const short8*)&Ah[16 * s + c16][ks * 32 + quad * 8];
      al[s] = *(const short8*)&Al[16 * s + c16][ks * 32 + quad * 8];
    }
    #pragma unroll
    for (int j = 0; j < 2; ++j) {
      const unsigned short* bp = Wf + (size_t)(((2 * w + j) * 4 + ks) * 64 + lane) * 8;
      short8 bh = *(const short8*)bp;
      short8 bl = *(const short8*)(bp + 16384);
      #pragma unroll
      for (int s = 0; s < 4; ++s) {
        acc[j][s] = __builtin_amdgcn_mfma_f32_16x16x32_bf16(ah[s], bh, acc[j][s], 0, 0, 0);
        acc[j][s] = __builtin_amdgcn_mfma_f32_16x16x32_bf16(ah[s], bl, acc[j][s], 0, 0, 0);
        acc[j][s] = __builtin_amdgcn_mfma_f32_16x16x32_bf16(al[s], bh, acc[j][s], 0, 0, 0);
      }
    }
  }
}

// ---- q slice: 1 pass + fp32 write ----
__device__ __forceinline__ void proj_q(const unsigned short Ah[][LDA],
    const unsigned short Al[][LDA], int t, int m0,
    const unsigned short* __restrict__ WqF, const float* __restrict__ bq0,
    float* __restrict__ Pq) {
  const int w = t >> 6, c16 = t & 15, quad = (t & 63) >> 4;
  f32x4 acc[2][4] = {};
  mfma_pass(Ah, Al, t, WqF, acc);
  #pragma unroll
  for (int j = 0; j < 2; ++j) {
    const int col = (2 * w + j) * 16 + c16;
    const float bb = bq0[col];
    #pragma unroll
    for (int s = 0; s < 4; ++s)
      #pragma unroll
      for (int r = 0; r < 4; ++r) {
        int m = m0 + 16 * s + quad * 4 + r;
        Pq[(size_t)m * HID + col] = acc[j][s][r] + bb;
      }
  }
}

// ---- k|v slice: K pass (packed to 16 u32) then V pass, full-dword fp16 pair write ----
__device__ __forceinline__ void proj_kv(const unsigned short Ah[][LDA],
    const unsigned short Al[][LDA], int t, int m0,
    const unsigned short* __restrict__ WfK, const float* __restrict__ bK,
    const float* __restrict__ bV, unsigned int* __restrict__ dst) {
  const int w = t >> 6, c16 = t & 15, quad = (t & 63) >> 4;
  unsigned kp[2][4][2];
  {
    f32x4 accK[2][4] = {};
    mfma_pass(Ah, Al, t, WfK, accK);
    #pragma unroll
    for (int j = 0; j < 2; ++j) {
      const float bbk = bK[(2 * w + j) * 16 + c16];
      #pragma unroll
      for (int s = 0; s < 4; ++s)
        #pragma unroll
        for (int rr = 0; rr < 2; ++rr)
          kp[j][s][rr] = (unsigned)f2h(accK[j][s][2 * rr] + bbk)
                       | ((unsigned)f2h(accK[j][s][2 * rr + 1] + bbk) << 16);
    }
  }
  f32x4 accV[2][4] = {};
  mfma_pass(Ah, Al, t, WfK + 32768, accV);
  #pragma unroll
  for (int j = 0; j < 2; ++j) {
    const int col = (2 * w + j) * 16 + c16;
    const float bbv = bV[col];
    #pragma unroll
    for (int s = 0; s < 4; ++s)
      #pragma unroll
      for (int r = 0; r < 4; ++r) {
        int m = m0 + 16 * s + quad * 4 + r;
        unsigned pk = (kp[j][s][r >> 1] >> ((r & 1) * 16)) & 0xffffu;
        unsigned pv = (unsigned)f2h(accV[j][s][r] + bbv);
        dst[(size_t)m * HID + col] = pk | (pv << 16);
      }
  }
}

// ================= k_sf: weight-combine (via LDS, no CW round-trip) + frag, one launch ========
__global__ __launch_bounds__(256) void k_sf(
    const float* __restrict__ Wk, const float* __restrict__ Wv,
    const float* __restrict__ bk, const float* __restrict__ bv,
    const float* __restrict__ a_rel, const float* __restrict__ m_rel,
    const float* __restrict__ p_rel, const float* __restrict__ Wq,
    const float* __restrict__ Wa, float* __restrict__ CB,
    unsigned short* __restrict__ FW) {
  __shared__ float cwl[HID * HID];   // 64 KB
  int m = blockIdx.x, t = threadIdx.x;
  unsigned short* hi = FW + (size_t)m * 32768;
  unsigned short* lo = hi + 16384;
  if (m < 16) {                      // combine K/V mats into LDS, bias to CB, then frag
    int l = m >> 2, mat = m & 3;
    int rel = mat >> 1;
    int isK = ((mat & 1) == 0);
    const float* W  = (isK ? Wk : Wv) + (size_t)(l * 2) * HID * HID;
    const float* bb = (isK ? bk : bv) + (l * 2) * HID;
    const float* R  = (isK ? a_rel : m_rel) + (size_t)((l * 2 + rel) * NH) * DH * DH;
    for (int o = t; o < HID * HID; o += 256) {
      int j = o >> 7, c = o & 127;
      int h = j >> 4, e = j & 15;
      float sc = isK ? (p_rel[(l * 2 + rel) * NH + h] * SCALE) : 1.0f;
      float s = 0.f;
      #pragma unroll
      for (int d = 0; d < DH; ++d)
        s += W[(size_t)(h * DH + d) * HID + c] * R[h * 256 + d * 16 + e];
      cwl[j * HID + c] = s * sc;
    }
    if (t < HID) {
      int j = t, h = j >> 4, e = j & 15;
      float sc = isK ? (p_rel[(l * 2 + rel) * NH + h] * SCALE) : 1.0f;
      float s = 0.f;
      #pragma unroll
      for (int d = 0; d < DH; ++d) s += bb[h * DH + d] * R[h * 256 + d * 16 + e];
      CB[m * HID + j] = s * sc;
    }
    __syncthreads();
    for (int idx = t; idx < 16384; idx += 256) {
      int j = idx & 7, lane = (idx >> 3) & 63, ks = (idx >> 9) & 3, nt = idx >> 11;
      int n = nt * 16 + (lane & 15);
      int k = ks * 32 + (lane >> 4) * 8 + j;
      float x = cwl[n * HID + k];
      unsigned short h = f2bf(x);
      hi[idx] = h;
      lo[idx] = f2bf(x - bf2f(h));
    }
    return;
  }
  const float* src = (m < 20) ? (Wq + (size_t)((m - 16) * 2) * HID * HID)
                              : (Wa + (size_t)((m - 20) * 2) * HID * HID);
  for (int idx = t; idx < 16384; idx += 256) {
    int j = idx & 7, lane = (idx >> 3) & 63, ks = (idx >> 9) & 3, nt = idx >> 11;
    int n = nt * 16 + (lane & 15);
    int k = ks * 32 + (lane >> 4) * 8 + j;
    float x = src[(size_t)n * HID + k];
    unsigned short h = f2bf(x);
    hi[idx] = h;
    lo[idx] = f2bf(x - bf2f(h));
  }
}

// ================= k_pre: bucket-scatter (8/thr ILP) + layer-0 proj slices + qv0 ==============
// Scatter blocks all resident from t=0 (3 blk/CU at VGPR~144); proj drains under them.
// r5 lesson: scatter ILP matters (1/thr=104us, 4/thr=72us) -> 8/thr.
struct PreArgs {
  const int *src0, *dst0, *src1, *dst1;
  int *cnt0, *cnt1, *colB0, *colB1;
  const float* x_op; const unsigned short* FW; const float *bq, *CB;
  float* Pq; unsigned int *Pkv0, *Pkv1;
  const float *x_v, *Wq1, *bq1; float* qv;
};

__launch_bounds__(256)
__global__ void k_pre(PreArgs a) {
  __shared__ SMu sm;
  int bx = blockIdx.x, t = threadIdx.x;
  if (bx < E0E / 2048) {                     // edge0 bucket scatter (8 edges/thread ILP)
    int base = bx * 2048 + t;
    #pragma unroll
    for (int i = 0; i < 8; ++i) {
      int e = base + i * 256;
      int d = a.dst0[e];
      int pos = atomicAdd(&a.cnt0[d], 1);
      if (pos < CAP0) a.colB0[((size_t)d << 6) + pos] = a.src0[e];
    }
    return;
  }
  bx -= E0E / 2048;
  if (bx < NN / 2048) {                      // edge1 bucket scatter
    int base = bx * 2048 + t;
    #pragma unroll
    for (int i = 0; i < 8; ++i) {
      int e = base + i * 256;
      int d = a.dst1[e];
      int pos = atomicAdd(&a.cnt1[d], 1);
      if (pos < CAP1) a.colB1[((size_t)d << 10) + pos] = a.src1[e];
    }
    return;
  }
  bx -= NN / 2048;
  if (bx < 3 * (NN / 64)) {                  // layer-0 projection slice: tile | slice y
    int y = bx >> 9, tile = bx & 511;
    int m0 = tile * 64;
    stage_A(sm.a.Ah, sm.a.Al, t, a.x_op, m0, 0);
    __syncthreads();
    if (y == 0)      proj_q (sm.a.Ah, sm.a.Al, t, m0, a.FW + (size_t)16 * 32768, a.bq, a.Pq);
    else if (y == 1) proj_kv(sm.a.Ah, sm.a.Al, t, m0, a.FW, a.CB, a.CB + HID, a.Pkv0);
    else             proj_kv(sm.a.Ah, sm.a.Al, t, m0, a.FW + (size_t)2 * 32768,
                             a.CB + 2 * HID, a.CB + 3 * HID, a.Pkv1);
    return;
  }
  bx -= 3 * (NN / 64);                       // qv0 for vnode bx
  if (t < HID) sm.v.xr[t] = a.x_v[bx * HID + t];
  __syncthreads();
  if (t < HID) {
    float s = a.bq1[t];
    const float4* wr = (const float4*)(a.Wq1 + (size_t)t * HID);
    const float4* xx = (const float4*)sm.v.xr;
    #pragma unroll 8
    for (int c = 0; c < HID / 4; ++c) {
      float4 w4 = wr[c], x4 = xx[c];
      s += x4.x * w4.x + x4.y * w4.y + x4.z * w4.z + x4.w * w4.w;
    }
    a.qv[bx * HID + t] = s;
  }
}

// ================= k_edges: edge0 (blocks < e0blocks; DEAD at l=3) + edge1 =====================
__launch_bounds__(256)
__global__ void k_edges(const float* __restrict__ Pq, const unsigned int* __restrict__ Pkv0,
                        const unsigned int* __restrict__ Pkv1,
                        const int* __restrict__ cnt0, const int* __restrict__ colB0,
                        float* __restrict__ agg, const float* __restrict__ qv,
                        const int* __restrict__ cnt1, const int* __restrict__ colB1,
                        float* __restrict__ part, int e0blocks) {
  int lane = threadIdx.x & 63;
  if (blockIdx.x < e0blocks) {
    int n = blockIdx.x * 4 + (threadIdx.x >> 6);
    float2 q = *(const float2*)(Pq + (size_t)n * HID + 2 * lane);
    int cnt = cnt0[n]; if (cnt > CAP0) cnt = CAP0;
    int e = n << 6, e1 = (n << 6) + cnt;
    float acc0 = 0.f, acc1 = 0.f, wsum = 0.f;
    for (; e + 8 <= e1; e += 8) {
      const uint2* r[8];
      #pragma unroll
      for (int u = 0; u < 8; ++u)
        r[u] = (const uint2*)(Pkv0 + ((size_t)colB0[e + u] << 7) + 2 * lane);
      uint2 kv[8];
      #pragma unroll
      for (int u = 0; u < 8; ++u) kv[u] = *r[u];
      float p[8];
      #pragma unroll
      for (int u = 0; u < 8; ++u)
        p[u] = q.x * f16lo(kv[u].x) + q.y * f16lo(kv[u].y);
      #pragma unroll
      for (int u = 0; u < 8; ++u) {
        p[u] += __shfl_xor(p[u], 1); p[u] += __shfl_xor(p[u], 2); p[u] += __shfl_xor(p[u], 4);
      }
      #pragma unroll
      for (int u = 0; u < 8; ++u) {
        float wg = __expf(p[u]);
        wsum += wg; acc0 += wg * f16hi(kv[u].x); acc1 += wg * f16hi(kv[u].y);
      }
    }
    for (; e < e1; ++e) {
      uint2 kv = *(const uint2*)(Pkv0 + ((size_t)colB0[e] << 7) + 2 * lane);
      float p = q.x * f16lo(kv.x) + q.y * f16lo(kv.y);
      p += __shfl_xor(p, 1); p += __shfl_xor(p, 2); p += __shfl_xor(p, 4);
      float wg = __expf(p);
      wsum += wg; acc0 += wg * f16hi(kv.x); acc1 += wg * f16hi(kv.y);
    }
    float inv = 1.0f / (wsum + 1e-16f);
    *(float2*)(agg + (size_t)n * HID + 2 * lane) = make_float2(acc0 * inv, acc1 * inv);
  } else {
    int b2 = blockIdx.x - e0blocks;
    int g = b2 >> 3, ch = b2 & 7;
    int w = threadIdx.x >> 6;
    int slot = ch * 4 + w;
    float2 q = *(const float2*)(qv + g * HID + 2 * lane);
    int tot = cnt1[g]; if (tot > CAP1) tot = CAP1;
    int base = g << 10;
    int len = (tot + 31) >> 5;
    int s0 = base + slot * len;
    int s1 = s0 + len; int lim = base + tot; if (s1 > lim) s1 = lim;
    float acc0 = 0.f, acc1 = 0.f, wsum = 0.f;
    int e = s0;
    for (; e + 4 <= s1; e += 4) {
      uint2 ka = *(const uint2*)(Pkv1 + ((size_t)colB1[e]     << 7) + 2 * lane);
      uint2 kb = *(const uint2*)(Pkv1 + ((size_t)colB1[e + 1] << 7) + 2 * lane);
      uint2 kc = *(const uint2*)(Pkv1 + ((size_t)colB1[e + 2] << 7) + 2 * lane);
      uint2 kd = *(const uint2*)(Pkv1 + ((size_t)colB1[e + 3] << 7) + 2 * lane);
      float pa = q.x * f16lo(ka.x) + q.y * f16lo(ka.y);
      float pb = q.x * f16lo(kb.x) + q.y * f16lo(kb.y);
      float pc = q.x * f16lo(kc.x) + q.y * f16lo(kc.y);
      float pd = q.x * f16lo(kd.x) + q.y * f16lo(kd.y);
      pa += __shfl_xor(pa, 1); pb += __shfl_xor(pb, 1); pc += __shfl_xor(pc, 1); pd += __shfl_xor(pd, 1);
      pa += __shfl_xor(pa, 2); pb += __shfl_xor(pb, 2); pc += __shfl_xor(pc, 2); pd += __shfl_xor(pd, 2);
      pa += __shfl_xor(pa, 4); pb += __shfl_xor(pb, 4); pc += __shfl_xor(pc, 4); pd += __shfl_xor(pd, 4);
      float wa = __expf(pa), wb = __expf(pb), wc = __expf(pc), wd = __expf(pd);
      wsum += (wa + wb) + (wc + wd);
      acc0 += wa * f16hi(ka.x) + wb * f16hi(kb.x) + wc * f16hi(kc.x) + wd * f16hi(kd.x);
      acc1 += wa * f16hi(ka.y) + wb * f16hi(kb.y) + wc * f16hi(kc.y) + wd * f16hi(kd.y);
    }
    for (; e < s1; ++e) {
      uint2 kv = *(const uint2*)(Pkv1 + ((size_t)colB1[e] << 7) + 2 * lane);
      float p = q.x * f16lo(kv.x) + q.y * f16lo(kv.y);
      p += __shfl_xor(p, 1); p += __shfl_xor(p, 2); p += __shfl_xor(p, 4);
      float ww = __expf(p);
      wsum += ww; acc0 += ww * f16hi(kv.x); acc1 += ww * f16hi(kv.y);
    }
    float* pp = part + (size_t)(g * 32 + slot) * 192;
    pp[lane] = acc0; pp[64 + lane] = acc1; pp[128 + lane] = wsum;
  }
}

// ================= k_post_a: post-GEMM + skip -> xop_cur (1 pass/block) + vtail ===============
// r6's fused k_post ran 6 serial passes/block at 0.83 TB/s, Occupancy 10% — latency-bound
// chain. Split: _a does ONLY the post pass (short chain); _b does proj slices (k_pre-proven
// structure, no redundancy). xop double-buffered (xold != xcur) so no r7-style race.
struct PArgs {
  const float *agg; const unsigned short *WaF_l; const float *ba_l0, *skip_l0, *xold;
  float *xcur;
  const float *part, *Wa_l1, *ba_l1, *skip_l1, *xvold;
  float *xv, *outsv_l, *qv;
  const float *Wq_n1, *bq_n1;
  int do_qv, vonly;
};

__device__ __forceinline__ void vtail(SMu& sm, int t, int v, const PArgs& f) {
  if (t < 64) {
    float a0 = 0.f, a1 = 0.f, ws2 = 0.f;
    for (int s = 0; s < 32; ++s) {
      const float* p = f.part + (size_t)(v * 32 + s) * 192;
      a0 += p[t]; a1 += p[64 + t]; ws2 += p[128 + t];
    }
    float inv = 1.0f / (ws2 + 1e-16f);
    sm.v.xr[2 * t]     = gelu_f(a0 * inv);
    sm.v.xr[2 * t + 1] = gelu_f(a1 * inv);
  }
  __syncthreads();
  if (t < HID) {
    float s = f.ba_l1[t];
    const float4* wr = (const float4*)(f.Wa_l1 + (size_t)t * HID);
    const float4* xx = (const float4*)sm.v.xr;
    #pragma unroll 8
    for (int c = 0; c < HID / 4; ++c) {
      float4 w4 = wr[c], x4 = xx[c];
      s += x4.x * w4.x + x4.y * w4.y + x4.z * w4.z + x4.w * w4.w;
    }
    float gg = sigmoid_f(*f.skip_l1);
    float nv2 = gg * s + (1.f - gg) * f.xvold[v * HID + t];
    f.xv[v * HID + t] = nv2;
    f.outsv_l[v * HID + t] = nv2;
    sm.v.xn[t] = nv2;
  }
  __syncthreads();
  if (f.do_qv && t < HID) {
    float s = f.bq_n1[t];
    const float4* wr = (const float4*)(f.Wq_n1 + (size_t)t * HID);
    const float4* xx = (const float4*)sm.v.xn;
    #pragma unroll 8
    for (int c = 0; c < HID / 4; ++c) {
      float4 w4 = wr[c], x4 = xx[c];
      s += x4.x * w4.x + x4.y * w4.y + x4.z * w4.z + x4.w * w4.w;
    }
    f.qv[v * HID + t] = s;
  }
}

__launch_bounds__(256)
__global__ void k_post_a(PArgs f) {
  __shared__ SMu sm;
  const int t = threadIdx.x;
  int bx = blockIdx.x;
  if (f.vonly) { vtail(sm, t, bx, f); return; }
  if (bx >= NN / 64) { vtail(sm, t, bx - NN / 64, f); return; }
  const int m0 = bx * 64;
  stage_A(sm.a.Ah, sm.a.Al, t, f.agg, m0, 1);
  __syncthreads();
  f32x4 acc[2][4] = {};
  mfma_pass(sm.a.Ah, sm.a.Al, t, f.WaF_l, acc);
  const int w = t >> 6, c16 = t & 15, quad = (t & 63) >> 4;
  float g = sigmoid_f(*f.skip_l0), gm1 = 1.0f - g;
  #pragma unroll
  for (int j = 0; j < 2; ++j) {
    const int col = (2 * w + j) * 16 + c16;
    const float bb = f.ba_l0[col];
    #pragma unroll
    for (int s = 0; s < 4; ++s)
      #pragma unroll
      for (int r = 0; r < 4; ++r) {
        int lm = 16 * s + quad * 4 + r;
        float v = acc[j][s][r] + bb;
        f.xcur[(size_t)(m0 + lm) * HID + col] =
            g * v + gm1 * f.xold[(size_t)(m0 + lm) * HID + col];
      }
  }
}

// ================= k_post_b: next-layer proj slices from xop_cur (1-2 passes/block) ===========
__launch_bounds__(256)
__global__ void k_post_b(const float* __restrict__ X, const unsigned short* __restrict__ WqF,
                         const unsigned short* __restrict__ CWF,
                         const float* __restrict__ bq0, const float* __restrict__ CBl,
                         float* __restrict__ Pq, unsigned int* __restrict__ Pkv0,
                         unsigned int* __restrict__ Pkv1, int y_base) {
  __shared__ SMu sm;
  const int t = threadIdx.x;
  int y = y_base + (blockIdx.x >> 9), tile = blockIdx.x & 511;
  int m0 = tile * 64;
  stage_A(sm.a.Ah, sm.a.Al, t, X, m0, 0);
  __syncthreads();
  if (y == 0)      proj_q (sm.a.Ah, sm.a.Al, t, m0, WqF, bq0, Pq);
  else if (y == 1) proj_kv(sm.a.Ah, sm.a.Al, t, m0, CWF, CBl, CBl + HID, Pkv0);
  else             proj_kv(sm.a.Ah, sm.a.Al, t, m0, CWF + (size_t)2 * 32768,
                           CBl + 2 * HID, CBl + 3 * HID, Pkv1);
}

// ================= JK attention + node/graph MLPs =============================================
struct TailW {
  const float *win, *bin, *wout, *bout;
  const float *nw0, *nb0, *nw1, *nb1, *nw2, *nb2, *nw3, *nb3, *nw4, *nb4, *nw5, *nb5, *nw6, *nb6;
  const float *gw0, *gb0, *gw1, *gb1;
};

__launch_bounds__(128)
__global__ void k_final(const float* __restrict__ outsv, TailW tw, float* __restrict__ outp) {
  __shared__ float xs[4][HID], qq[4][HID], kk[4][HID], vv[4][HID], oo[4][HID];
  __shared__ float att[NH][4][4];
  __shared__ float hb[HID], tb[64];
  int b = blockIdx.x, t = threadIdx.x;
  for (int l = 0; l < 4; ++l) xs[l][t] = outsv[(size_t)(l * NV + b) * HID + t];
  __syncthreads();
  for (int l = 0; l < 4; ++l) {
    float sq = tw.bin[t], sk = tw.bin[t + 128], sv = tw.bin[t + 256];
    const float* wq = tw.win + (size_t)t * HID;
    const float* wk = tw.win + (size_t)(t + 128) * HID;
    const float* wv = tw.win + (size_t)(t + 256) * HID;
    for (int c = 0; c < HID; ++c) {
      float x = xs[l][c];
      sq += x * wq[c]; sk += x * wk[c]; sv += x * wv[c];
    }
    qq[l][t] = sq; kk[l][t] = sk; vv[l][t] = sv;
  }
  __syncthreads();
  {
    int h = t >> 4, ql = (t >> 2) & 3, kl = t & 3;
    float s = 0.f;
    #pragma unroll
    for (int d = 0; d < DH; ++d) s += qq[ql][h * DH + d] * kk[kl][h * DH + d];
    att[h][ql][kl] = s * SCALE;
  }
  __syncthreads();
  if (t < 32) {
    int h = t >> 2, ql = t & 3;
    float m = att[h][ql][0];
    for (int k2 = 1; k2 < 4; ++k2) m = fmaxf(m, att[h][ql][k2]);
    float e[4], s = 0.f;
    for (int k2 = 0; k2 < 4; ++k2) { e[k2] = __expf(att[h][ql][k2] - m); s += e[k2]; }
    for (int k2 = 0; k2 < 4; ++k2) att[h][ql][k2] = e[k2] / s;
  }
  __syncthreads();
  {
    int h = t >> 4;
    #pragma unroll
    for (int ql = 0; ql < 4; ++ql) {
      float s = 0.f;
      #pragma unroll
      for (int kl = 0; kl < 4; ++kl) s += att[h][ql][kl] * vv[kl][t];
      oo[ql][t] = s;
    }
  }
  __syncthreads();
  {
    float s = 0.f;
    const float* wr = tw.wout + (size_t)t * HID;
    for (int l = 0; l < 4; ++l) {
      float ss = tw.bout[t];
      for (int c = 0; c < HID; ++c) ss += oo[l][c] * wr[c];
      s += ss;
    }
    hb[t] = s;
  }
  __syncthreads();
  if (t < 64) { float s = tw.nb0[t]; const float* wr = tw.nw0 + t * 128; for (int c = 0; c < 128; ++c) s += hb[c] * wr[c]; tb[t] = gelu_f(s); }
  __syncthreads();
  if (t < 32) { float s = tw.nb1[t]; const float* wr = tw.nw1 + t * 64;  for (int c = 0; c < 64;  ++c) s += tb[c] * wr[c]; hb[t] = gelu_f(s); }
  __syncthreads();
  if (t < 16) { float s = tw.nb2[t]; const float* wr = tw.nw2 + t * 32;  for (int c = 0; c < 32;  ++c) s += hb[c] * wr[c]; tb[t] = gelu_f(s); }
  __syncthreads();
  if (t < 8)  { float s = tw.nb3[t]; const float* wr = tw.nw3 + t * 16;  for (int c = 0; c < 16;  ++c) s += tb[c] * wr[c]; hb[t] = gelu_f(s); }
  __syncthreads();
  if (t < 4)  { float s = tw.nb4[t]; const float* wr = tw.nw4 + t * 8;   for (int c = 0; c < 8;   ++c) s += hb[c] * wr[c]; tb[t] = gelu_f(s); }
  __syncthreads();
  if (t < 2)  { float s = tw.nb5[t]; const float* wr = tw.nw5 + t * 4;   for (int c = 0; c < 4;   ++c) s += tb[c] * wr[c]; hb[t] = gelu_f(s); }
  __syncthreads();
  if (t == 0) {
    float s = hb[0] * tw.nw6[0] + hb[1] * tw.nw6[1] + tw.nb6[0];
    float g0 = gelu_f(s * tw.gw0[0] + tw.gb0[0]);
    float g1 = gelu_f(s * tw.gw0[1] + tw.gb0[1]);
    outp[b] = g0 * tw.gw1[0] + g1 * tw.gw1[1] + tw.gb1[0];
  }
}

// ================= host =======================================================================
extern "C" void kernel_launch(void* const* d_in, const int* in_sizes, int n_in,
                              void* d_out, int out_size, void* d_ws, size_t ws_size,
                              hipStream_t stream) {
  const float* x_op = (const float*)d_in[0];
  const float* x_v  = (const float*)d_in[1];
  const int*   ei0  = (const int*)d_in[2];
  const int*   ei1  = (const int*)d_in[3];
  const float* Wk   = (const float*)d_in[4];
  const float* Wq   = (const float*)d_in[5];
  const float* Wv   = (const float*)d_in[6];
  const float* Wa   = (const float*)d_in[7];
  const float* bk   = (const float*)d_in[8];
  const float* bq   = (const float*)d_in[9];
  const float* bv   = (const float*)d_in[10];
  const float* ba   = (const float*)d_in[11];
  const float* skip = (const float*)d_in[12];
  const float* a_rel = (const float*)d_in[13];
  const float* m_rel = (const float*)d_in[14];
  const float* p_rel = (const float*)d_in[15];
  (void)in_sizes; (void)n_in; (void)out_size; (void)ws_size;

  char* wsp = (char*)d_ws;
  size_t off = 0;
  auto alloc = [&](size_t bytes) -> void* {
    void* p = wsp + off;
    off += (bytes + 255) & ~(size_t)255;
    return p;
  };
  float* Pq    = (float*)alloc((size_t)NN * HID * 4);
  unsigned int* Pkv0 = (unsigned int*)alloc((size_t)NN * HID * 4);  // fp16 k|v packed per dword
  unsigned int* Pkv1 = (unsigned int*)alloc((size_t)NN * HID * 4);
  float* xopA  = (float*)alloc((size_t)NN * HID * 4);
  float* xopB  = (float*)alloc((size_t)NN * HID * 4);
  float* agg   = (float*)alloc((size_t)NN * HID * 4);
  float* CB    = (float*)alloc((size_t)16 * HID * 4);
  unsigned short* FW = (unsigned short*)alloc((size_t)24 * 32768 * 2);  // 1.57 MB frag weights
  float* xv    = (float*)alloc((size_t)NV * HID * 4);
  float* qv    = (float*)alloc((size_t)NV * HID * 4);
  float* outsv = (float*)alloc((size_t)NL * NV * HID * 4);
  float* part  = (float*)alloc((size_t)NV * 32 * 192 * 4);
  int* cnt0    = (int*)alloc((size_t)NN * 4);
  int* colB0   = (int*)alloc((size_t)NN * CAP0 * 4);
  int* cnt1    = (int*)alloc((size_t)NV * 4);
  int* colB1   = (int*)alloc((size_t)NV * CAP1 * 4);

  hipMemsetAsync(cnt0, 0, (size_t)NN * 4, stream);
  hipMemsetAsync(cnt1, 0, (size_t)NV * 4, stream);

  k_sf<<<24, 256, 0, stream>>>(Wk, Wv, bk, bv, a_rel, m_rel, p_rel, Wq, Wa, CB, FW);

  PreArgs pa;
  pa.src0 = ei0; pa.dst0 = ei0 + E0E;
  pa.src1 = ei1; pa.dst1 = ei1 + NN;
  pa.cnt0 = cnt0; pa.cnt1 = cnt1; pa.colB0 = colB0; pa.colB1 = colB1;
  pa.x_op = x_op; pa.FW = FW; pa.bq = bq; pa.CB = CB;
  pa.Pq = Pq; pa.Pkv0 = Pkv0; pa.Pkv1 = Pkv1;
  pa.x_v = x_v; pa.Wq1 = Wq + (size_t)1 * HID * HID; pa.bq1 = bq + HID; pa.qv = qv;
  k_pre<<<E0E / 2048 + NN / 2048 + 3 * (NN / 64) + NV, 256, 0, stream>>>(pa);

  for (int l = 0; l < NL; ++l) {
    int e0b = (l < NL - 1) ? NN / 4 : 0;       // l=3 edge0 aggregation is DEAD (x_op unused)
    k_edges<<<e0b + NV * 8, 256, 0, stream>>>(Pq, Pkv0, Pkv1, cnt0, colB0, agg,
                                              qv, cnt1, colB1, part, e0b);
    float* xold = (l == 0) ? (float*)x_op : ((l & 1) ? xopA : xopB);
    float* xcur = (l & 1) ? xopB : xopA;       // l=0->A, l=1->B, l=2->A
    PArgs f;
    f.agg = agg;
    f.WaF_l = FW + (size_t)(20 + l) * 32768;
    f.ba_l0 = ba + (l * 2 + 0) * HID;
    f.skip_l0 = skip + l * 2 + 0;
    f.xold = xold;
    f.xcur = xcur;
    f.part = part;
    f.Wa_l1 = Wa + (size_t)(l * 2 + 1) * HID * HID;
    f.ba_l1 = ba + (l * 2 + 1) * HID;
    f.skip_l1 = skip + l * 2 + 1;
    f.xvold = (l == 0) ? x_v : xv;
    f.xv = xv;
    f.outsv_l = outsv + (size_t)l * NV * HID;
    f.qv = qv;
    int ln = (l + 1) & 3;
    f.Wq_n1 = Wq + (size_t)(ln * 2 + 1) * HID * HID;
    f.bq_n1 = bq + (ln * 2 + 1) * HID;
    f.do_qv = (l < NL - 1) ? 1 : 0;
    f.vonly = (l == NL - 1) ? 1 : 0;
    k_post_a<<<(l < NL - 1) ? (NN / 64 + NV) : NV, 256, 0, stream>>>(f);
    if (l < NL - 1) {
      // l=0,1 -> full q+kv0+kv1 (3 slices); l=2 -> only kv1 survives pruning (y_base=2)
      int nsl = (l < 2) ? 3 : 1;
      int yb  = (l < 2) ? 0 : 2;
      k_post_b<<<nsl * (NN / 64), 256, 0, stream>>>(
          xcur, FW + (size_t)(16 + ln) * 32768, FW + (size_t)(ln * 4) * 32768,
          bq + (size_t)ln * 2 * HID, CB + (size_t)ln * 4 * HID, Pq, Pkv0, Pkv1, yb);
    }
  }

  TailW tw;
  tw.win  = (const float*)d_in[16]; tw.bin  = (const float*)d_in[17];
  tw.wout = (const float*)d_in[18]; tw.bout = (const float*)d_in[19];
  tw.nw0 = (const float*)d_in[20]; tw.nb0 = (const float*)d_in[21];
  tw.nw1 = (const float*)d_in[22]; tw.nb1 = (const float*)d_in[23];
  tw.nw2 = (const float*)d_in[24]; tw.nb2 = (const float*)d_in[25];
  tw.nw3 = (const float*)d_in[26]; tw.nb3 = (const float*)d_in[27];
  tw.nw4 = (const float*)d_in[28]; tw.nb4 = (const float*)d_in[29];
  tw.nw5 = (const float*)d_in[30]; tw.nb5 = (const float*)d_in[31];
  tw.nw6 = (const float*)d_in[32]; tw.nb6 = (const float*)d_in[33];
  tw.gw0 = (const float*)d_in[34]; tw.gb0 = (const float*)d_in[35];
  tw.gw1 = (const float*)d_in[36]; tw.gb1 = (const float*)d_in[37];
  k_final<<<NV, 128, 0, stream>>>(outsv, tw, (float*)d_out);
}

// Round 12
// 556.234 us; speedup vs baseline: 1.3610x; 1.0079x over previous
//
#include <hip/hip_runtime.h>

#define NN   32768
#define NV   64
#define E0E  524288
#define HID  128
#define NL   4
#define NH   8
#define DH   16
#define SCALE 0.25f
#define LDA  136   // bf16 row stride for staged A (16B frag reads, 2-way alias)
#define CAP0 64
#define CAP1 1024

typedef __attribute__((ext_vector_type(8))) short short8;   // 8 bf16 = 4 VGPRs
typedef __attribute__((ext_vector_type(4))) float f32x4;

__device__ __forceinline__ float gelu_f(float x) {
  return 0.5f * x * (1.0f + erff(x * 0.7071067811865475f));
}
__device__ __forceinline__ float sigmoid_f(float x) {
  return 1.0f / (1.0f + __expf(-x));
}
__device__ __forceinline__ unsigned short f2bf(float x) {   // RN-even f32->bf16
  unsigned u = __float_as_uint(x);
  return (unsigned short)((u + 0x7FFFu + ((u >> 16) & 1u)) >> 16);
}
__device__ __forceinline__ float bf2f(unsigned short h) {
  return __uint_as_float(((unsigned)h) << 16);
}
__device__ __forceinline__ unsigned short f2h(float x) {
  union { _Float16 h; unsigned short u; } cv;
  cv.h = (_Float16)x;
  return cv.u;
}
__device__ __forceinline__ float h2f(unsigned short u) {
  union { _Float16 h; unsigned short u; } cv;
  cv.u = u;
  return (float)cv.h;
}
__device__ __forceinline__ float f16lo(unsigned u) { return h2f((unsigned short)(u & 0xffffu)); }
__device__ __forceinline__ float f16hi(unsigned u) { return h2f((unsigned short)(u >> 16)); }

union SMu {
  struct { unsigned short Ah[64][LDA]; unsigned short Al[64][LDA]; } a;  // 34816 B
  struct { float xr[HID]; float xn[HID]; } v;
};

// ---- stage 64xK=128 fp32 tile into split hi/lo bf16 LDS (coalesced float4 reads) ----
__device__ __forceinline__ void stage_A(unsigned short Ah[][LDA], unsigned short Al[][LDA],
                                        int t, const float* __restrict__ A, int m0, int gelu) {
  #pragma unroll
  for (int i = 0; i < 8; ++i) {
    int idx = t + 256 * i;            // float4 index over 64x32
    int m = idx >> 5, c4 = (idx & 31) * 4;
    float4 v = *(const float4*)(A + (size_t)(m0 + m) * HID + c4);
    if (gelu) { v.x = gelu_f(v.x); v.y = gelu_f(v.y); v.z = gelu_f(v.z); v.w = gelu_f(v.w); }
    unsigned short h0 = f2bf(v.x), h1 = f2bf(v.y), h2 = f2bf(v.z), h3 = f2bf(v.w);
    *(ushort4*)&Ah[m][c4] = make_ushort4(h0, h1, h2, h3);
    *(ushort4*)&Al[m][c4] = make_ushort4(f2bf(v.x - bf2f(h0)), f2bf(v.y - bf2f(h1)),
                                         f2bf(v.z - bf2f(h2)), f2bf(v.w - bf2f(h3)));
  }
}

// ---- MFMA split-bf16 single pass: 64x128 tile, K=128, B-reuse form (96 MFMAs/wave) ----
__device__ __forceinline__ void mfma_pass(const unsigned short Ah[][LDA],
    const unsigned short Al[][LDA], int t, const unsigned short* __restrict__ Wf,
    f32x4 acc[2][4]) {
  const int w = t >> 6, lane = t & 63, c16 = lane & 15, quad = lane >> 4;
  #pragma unroll
  for (int ks = 0; ks < 4; ++ks) {
    short8 ah[4], al[4];
    #pragma unroll
    for (int s = 0; s < 4; ++s) {
      ah[s] = *(const short8*)&Ah[16 * s + c16][ks * 32 + quad * 8];
      al[s] = *(const short8*)&Al[16 * s + c16][ks * 32 + quad * 8];
    }
    #pragma unroll
    for (int j = 0; j < 2; ++j) {
      const unsigned short* bp = Wf + (size_t)(((2 * w + j) * 4 + ks) * 64 + lane) * 8;
      short8 bh = *(const short8*)bp;
      short8 bl = *(const short8*)(bp + 16384);
      #pragma unroll
      for (int s = 0; s < 4; ++s) {
        acc[j][s] = __builtin_amdgcn_mfma_f32_16x16x32_bf16(ah[s], bh, acc[j][s], 0, 0, 0);
        acc[j][s] = __builtin_amdgcn_mfma_f32_16x16x32_bf16(ah[s], bl, acc[j][s], 0, 0, 0);
        acc[j][s] = __builtin_amdgcn_mfma_f32_16x16x32_bf16(al[s], bh, acc[j][s], 0, 0, 0);
      }
    }
  }
}

// ---- q slice: 1 pass + fp32 write ----
__device__ __forceinline__ void proj_q(const unsigned short Ah[][LDA],
    const unsigned short Al[][LDA], int t, int m0,
    const unsigned short* __restrict__ WqF, const float* __restrict__ bq0,
    float* __restrict__ Pq) {
  const int w = t >> 6, c16 = t & 15, quad = (t & 63) >> 4;
  f32x4 acc[2][4] = {};
  mfma_pass(Ah, Al, t, WqF, acc);
  #pragma unroll
  for (int j = 0; j < 2; ++j) {
    const int col = (2 * w + j) * 16 + c16;
    const float bb = bq0[col];
    #pragma unroll
    for (int s = 0; s < 4; ++s)
      #pragma unroll
      for (int r = 0; r < 4; ++r) {
        int m = m0 + 16 * s + quad * 4 + r;
        Pq[(size_t)m * HID + col] = acc[j][s][r] + bb;
      }
  }
}

// ---- k|v slice: K pass (packed to 16 u32) then V pass, full-dword fp16 pair write ----
__device__ __forceinline__ void proj_kv(const unsigned short Ah[][LDA],
    const unsigned short Al[][LDA], int t, int m0,
    const unsigned short* __restrict__ WfK, const float* __restrict__ bK,
    const float* __restrict__ bV, unsigned int* __restrict__ dst) {
  const int w = t >> 6, c16 = t & 15, quad = (t & 63) >> 4;
  unsigned kp[2][4][2];
  {
    f32x4 accK[2][4] = {};
    mfma_pass(Ah, Al, t, WfK, accK);
    #pragma unroll
    for (int j = 0; j < 2; ++j) {
      const float bbk = bK[(2 * w + j) * 16 + c16];
      #pragma unroll
      for (int s = 0; s < 4; ++s)
        #pragma unroll
        for (int rr = 0; rr < 2; ++rr)
          kp[j][s][rr] = (unsigned)f2h(accK[j][s][2 * rr] + bbk)
                       | ((unsigned)f2h(accK[j][s][2 * rr + 1] + bbk) << 16);
    }
  }
  f32x4 accV[2][4] = {};
  mfma_pass(Ah, Al, t, WfK + 32768, accV);
  #pragma unroll
  for (int j = 0; j < 2; ++j) {
    const int col = (2 * w + j) * 16 + c16;
    const float bbv = bV[col];
    #pragma unroll
    for (int s = 0; s < 4; ++s)
      #pragma unroll
      for (int r = 0; r < 4; ++r) {
        int m = m0 + 16 * s + quad * 4 + r;
        unsigned pk = (kp[j][s][r >> 1] >> ((r & 1) * 16)) & 0xffffu;
        unsigned pv = (unsigned)f2h(accV[j][s][r] + bbv);
        dst[(size_t)m * HID + col] = pk | (pv << 16);
      }
  }
}

// ================= k_sf: weight-combine (via LDS) + frag + cnt zeroing, one launch ============
__global__ __launch_bounds__(256) void k_sf(
    const float* __restrict__ Wk, const float* __restrict__ Wv,
    const float* __restrict__ bk, const float* __restrict__ bv,
    const float* __restrict__ a_rel, const float* __restrict__ m_rel,
    const float* __restrict__ p_rel, const float* __restrict__ Wq,
    const float* __restrict__ Wa, float* __restrict__ CB,
    unsigned short* __restrict__ FW, int* __restrict__ cnt0, int* __restrict__ cnt1) {
  __shared__ float cwl[HID * HID];   // 64 KB
  int m = blockIdx.x, t = threadIdx.x;
  if (m >= 24) {                     // zero blocks (replaces 2 memset launches)
    int i = (m - 24) * 256 + t;
    cnt0[i] = 0;
    if (m == 24 && t < NV) cnt1[t] = 0;
    return;
  }
  unsigned short* hi = FW + (size_t)m * 32768;
  unsigned short* lo = hi + 16384;
  if (m < 16) {                      // combine K/V mats into LDS, bias to CB, then frag
    int l = m >> 2, mat = m & 3;
    int rel = mat >> 1;
    int isK = ((mat & 1) == 0);
    const float* W  = (isK ? Wk : Wv) + (size_t)(l * 2) * HID * HID;
    const float* bb = (isK ? bk : bv) + (l * 2) * HID;
    const float* R  = (isK ? a_rel : m_rel) + (size_t)((l * 2 + rel) * NH) * DH * DH;
    for (int o = t; o < HID * HID; o += 256) {
      int j = o >> 7, c = o & 127;
      int h = j >> 4, e = j & 15;
      float sc = isK ? (p_rel[(l * 2 + rel) * NH + h] * SCALE) : 1.0f;
      float s = 0.f;
      #pragma unroll
      for (int d = 0; d < DH; ++d)
        s += W[(size_t)(h * DH + d) * HID + c] * R[h * 256 + d * 16 + e];
      cwl[j * HID + c] = s * sc;
    }
    if (t < HID) {
      int j = t, h = j >> 4, e = j & 15;
      float sc = isK ? (p_rel[(l * 2 + rel) * NH + h] * SCALE) : 1.0f;
      float s = 0.f;
      #pragma unroll
      for (int d = 0; d < DH; ++d) s += bb[h * DH + d] * R[h * 256 + d * 16 + e];
      CB[m * HID + j] = s * sc;
    }
    __syncthreads();
    for (int idx = t; idx < 16384; idx += 256) {
      int j = idx & 7, lane = (idx >> 3) & 63, ks = (idx >> 9) & 3, nt = idx >> 11;
      int n = nt * 16 + (lane & 15);
      int k = ks * 32 + (lane >> 4) * 8 + j;
      float x = cwl[n * HID + k];
      unsigned short h = f2bf(x);
      hi[idx] = h;
      lo[idx] = f2bf(x - bf2f(h));
    }
    return;
  }
  const float* src = (m < 20) ? (Wq + (size_t)((m - 16) * 2) * HID * HID)
                              : (Wa + (size_t)((m - 20) * 2) * HID * HID);
  for (int idx = t; idx < 16384; idx += 256) {
    int j = idx & 7, lane = (idx >> 3) & 63, ks = (idx >> 9) & 3, nt = idx >> 11;
    int n = nt * 16 + (lane & 15);
    int k = ks * 32 + (lane >> 4) * 8 + j;
    float x = src[(size_t)n * HID + k];
    unsigned short h = f2bf(x);
    hi[idx] = h;
    lo[idx] = f2bf(x - bf2f(h));
  }
}

// ================= k_pre: bucket-scatter (16/thr ILP) + layer-0 proj slices + qv0 =============
// Scatter ILP trend: 1/thr=104us (r5), 8/thr=89us (r11) -> 16/thr. 136 scatter blocks still
// fill the machine at ~3 blk/CU; proj slice blocks drain under them.
struct PreArgs {
  const int *src0, *dst0, *src1, *dst1;
  int *cnt0, *cnt1, *colB0, *colB1;
  const float* x_op; const unsigned short* FW; const float *bq, *CB;
  float* Pq; unsigned int *Pkv0, *Pkv1;
  const float *x_v, *Wq1, *bq1; float* qv;
};

__launch_bounds__(256)
__global__ void k_pre(PreArgs a) {
  __shared__ SMu sm;
  int bx = blockIdx.x, t = threadIdx.x;
  if (bx < E0E / 4096) {                     // edge0 bucket scatter (16 edges/thread ILP)
    int base = bx * 4096 + t;
    #pragma unroll
    for (int i = 0; i < 16; ++i) {
      int e = base + i * 256;
      int d = a.dst0[e];
      int pos = atomicAdd(&a.cnt0[d], 1);
      if (pos < CAP0) a.colB0[((size_t)d << 6) + pos] = a.src0[e];
    }
    return;
  }
  bx -= E0E / 4096;
  if (bx < NN / 4096) {                      // edge1 bucket scatter
    int base = bx * 4096 + t;
    #pragma unroll
    for (int i = 0; i < 16; ++i) {
      int e = base + i * 256;
      int d = a.dst1[e];
      int pos = atomicAdd(&a.cnt1[d], 1);
      if (pos < CAP1) a.colB1[((size_t)d << 10) + pos] = a.src1[e];
    }
    return;
  }
  bx -= NN / 4096;
  if (bx < 3 * (NN / 64)) {                  // layer-0 projection slice: tile | slice y
    int y = bx >> 9, tile = bx & 511;
    int m0 = tile * 64;
    stage_A(sm.a.Ah, sm.a.Al, t, a.x_op, m0, 0);
    __syncthreads();
    if (y == 0)      proj_q (sm.a.Ah, sm.a.Al, t, m0, a.FW + (size_t)16 * 32768, a.bq, a.Pq);
    else if (y == 1) proj_kv(sm.a.Ah, sm.a.Al, t, m0, a.FW, a.CB, a.CB + HID, a.Pkv0);
    else             proj_kv(sm.a.Ah, sm.a.Al, t, m0, a.FW + (size_t)2 * 32768,
                             a.CB + 2 * HID, a.CB + 3 * HID, a.Pkv1);
    return;
  }
  bx -= 3 * (NN / 64);                       // qv0 for vnode bx
  if (t < HID) sm.v.xr[t] = a.x_v[bx * HID + t];
  __syncthreads();
  if (t < HID) {
    float s = a.bq1[t];
    const float4* wr = (const float4*)(a.Wq1 + (size_t)t * HID);
    const float4* xx = (const float4*)sm.v.xr;
    #pragma unroll 8
    for (int c = 0; c < HID / 4; ++c) {
      float4 w4 = wr[c], x4 = xx[c];
      s += x4.x * w4.x + x4.y * w4.y + x4.z * w4.z + x4.w * w4.w;
    }
    a.qv[bx * HID + t] = s;
  }
}

// ================= k_edges: edge0 (blocks < NN/4) + edge1 (for l=0..2) =========================
__launch_bounds__(256)
__global__ void k_edges(const float* __restrict__ Pq, const unsigned int* __restrict__ Pkv0,
                        const unsigned int* __restrict__ Pkv1,
                        const int* __restrict__ cnt0, const int* __restrict__ colB0,
                        float* __restrict__ agg, const float* __restrict__ qv,
                        const int* __restrict__ cnt1, const int* __restrict__ colB1,
                        float* __restrict__ part) {
  int lane = threadIdx.x & 63;
  if (blockIdx.x < NN / 4) {
    int n = blockIdx.x * 4 + (threadIdx.x >> 6);
    float2 q = *(const float2*)(Pq + (size_t)n * HID + 2 * lane);
    int cnt = cnt0[n]; if (cnt > CAP0) cnt = CAP0;
    int e = n << 6, e1 = (n << 6) + cnt;
    float acc0 = 0.f, acc1 = 0.f, wsum = 0.f;
    for (; e + 8 <= e1; e += 8) {
      const uint2* r[8];
      #pragma unroll
      for (int u = 0; u < 8; ++u)
        r[u] = (const uint2*)(Pkv0 + ((size_t)colB0[e + u] << 7) + 2 * lane);
      uint2 kv[8];
      #pragma unroll
      for (int u = 0; u < 8; ++u) kv[u] = *r[u];
      float p[8];
      #pragma unroll
      for (int u = 0; u < 8; ++u)
        p[u] = q.x * f16lo(kv[u].x) + q.y * f16lo(kv[u].y);
      #pragma unroll
      for (int u = 0; u < 8; ++u) {
        p[u] += __shfl_xor(p[u], 1); p[u] += __shfl_xor(p[u], 2); p[u] += __shfl_xor(p[u], 4);
      }
      #pragma unroll
      for (int u = 0; u < 8; ++u) {
        float wg = __expf(p[u]);
        wsum += wg; acc0 += wg * f16hi(kv[u].x); acc1 += wg * f16hi(kv[u].y);
      }
    }
    for (; e < e1; ++e) {
      uint2 kv = *(const uint2*)(Pkv0 + ((size_t)colB0[e] << 7) + 2 * lane);
      float p = q.x * f16lo(kv.x) + q.y * f16lo(kv.y);
      p += __shfl_xor(p, 1); p += __shfl_xor(p, 2); p += __shfl_xor(p, 4);
      float wg = __expf(p);
      wsum += wg; acc0 += wg * f16hi(kv.x); acc1 += wg * f16hi(kv.y);
    }
    float inv = 1.0f / (wsum + 1e-16f);
    *(float2*)(agg + (size_t)n * HID + 2 * lane) = make_float2(acc0 * inv, acc1 * inv);
  } else {
    int b2 = blockIdx.x - NN / 4;
    int g = b2 >> 3, ch = b2 & 7;
    int w = threadIdx.x >> 6;
    int slot = ch * 4 + w;
    float2 q = *(const float2*)(qv + g * HID + 2 * lane);
    int tot = cnt1[g]; if (tot > CAP1) tot = CAP1;
    int base = g << 10;
    int len = (tot + 31) >> 5;
    int s0 = base + slot * len;
    int s1 = s0 + len; int lim = base + tot; if (s1 > lim) s1 = lim;
    float acc0 = 0.f, acc1 = 0.f, wsum = 0.f;
    int e = s0;
    for (; e + 4 <= s1; e += 4) {
      uint2 ka = *(const uint2*)(Pkv1 + ((size_t)colB1[e]     << 7) + 2 * lane);
      uint2 kb = *(const uint2*)(Pkv1 + ((size_t)colB1[e + 1] << 7) + 2 * lane);
      uint2 kc = *(const uint2*)(Pkv1 + ((size_t)colB1[e + 2] << 7) + 2 * lane);
      uint2 kd = *(const uint2*)(Pkv1 + ((size_t)colB1[e + 3] << 7) + 2 * lane);
      float pa = q.x * f16lo(ka.x) + q.y * f16lo(ka.y);
      float pb = q.x * f16lo(kb.x) + q.y * f16lo(kb.y);
      float pc = q.x * f16lo(kc.x) + q.y * f16lo(kc.y);
      float pd = q.x * f16lo(kd.x) + q.y * f16lo(kd.y);
      pa += __shfl_xor(pa, 1); pb += __shfl_xor(pb, 1); pc += __shfl_xor(pc, 1); pd += __shfl_xor(pd, 1);
      pa += __shfl_xor(pa, 2); pb += __shfl_xor(pb, 2); pc += __shfl_xor(pc, 2); pd += __shfl_xor(pd, 2);
      pa += __shfl_xor(pa, 4); pb += __shfl_xor(pb, 4); pc += __shfl_xor(pc, 4); pd += __shfl_xor(pd, 4);
      float wa = __expf(pa), wb = __expf(pb), wc = __expf(pc), wd = __expf(pd);
      wsum += (wa + wb) + (wc + wd);
      acc0 += wa * f16hi(ka.x) + wb * f16hi(kb.x) + wc * f16hi(kc.x) + wd * f16hi(kd.x);
      acc1 += wa * f16hi(ka.y) + wb * f16hi(kb.y) + wc * f16hi(kc.y) + wd * f16hi(kd.y);
    }
    for (; e < s1; ++e) {
      uint2 kv = *(const uint2*)(Pkv1 + ((size_t)colB1[e] << 7) + 2 * lane);
      float p = q.x * f16lo(kv.x) + q.y * f16lo(kv.y);
      p += __shfl_xor(p, 1); p += __shfl_xor(p, 2); p += __shfl_xor(p, 4);
      float ww = __expf(p);
      wsum += ww; acc0 += ww * f16hi(kv.x); acc1 += ww * f16hi(kv.y);
    }
    float* pp = part + (size_t)(g * 32 + slot) * 192;
    pp[lane] = acc0; pp[64 + lane] = acc1; pp[128 + lane] = wsum;
  }
}

// ================= k_post_a: post-GEMM + skip -> xop_cur (1 pass/block) + vtail ===============
struct PArgs {
  const float *agg; const unsigned short *WaF_l; const float *ba_l0, *skip_l0, *xold;
  float *xcur;
  const float *part, *Wa_l1, *ba_l1, *skip_l1, *xvold;
  float *xv, *outsv_l, *qv;
  const float *Wq_n1, *bq_n1;
  int do_qv;
};

__device__ __forceinline__ void vtail(SMu& sm, int t, int v, const PArgs& f) {
  if (t < 64) {
    float a0 = 0.f, a1 = 0.f, ws2 = 0.f;
    for (int s = 0; s < 32; ++s) {
      const float* p = f.part + (size_t)(v * 32 + s) * 192;
      a0 += p[t]; a1 += p[64 + t]; ws2 += p[128 + t];
    }
    float inv = 1.0f / (ws2 + 1e-16f);
    sm.v.xr[2 * t]     = gelu_f(a0 * inv);
    sm.v.xr[2 * t + 1] = gelu_f(a1 * inv);
  }
  __syncthreads();
  if (t < HID) {
    float s = f.ba_l1[t];
    const float4* wr = (const float4*)(f.Wa_l1 + (size_t)t * HID);
    const float4* xx = (const float4*)sm.v.xr;
    #pragma unroll 8
    for (int c = 0; c < HID / 4; ++c) {
      float4 w4 = wr[c], x4 = xx[c];
      s += x4.x * w4.x + x4.y * w4.y + x4.z * w4.z + x4.w * w4.w;
    }
    float gg = sigmoid_f(*f.skip_l1);
    float nv2 = gg * s + (1.f - gg) * f.xvold[v * HID + t];
    f.xv[v * HID + t] = nv2;
    f.outsv_l[v * HID + t] = nv2;
    sm.v.xn[t] = nv2;
  }
  __syncthreads();
  if (f.do_qv && t < HID) {
    float s = f.bq_n1[t];
    const float4* wr = (const float4*)(f.Wq_n1 + (size_t)t * HID);
    const float4* xx = (const float4*)sm.v.xn;
    #pragma unroll 8
    for (int c = 0; c < HID / 4; ++c) {
      float4 w4 = wr[c], x4 = xx[c];
      s += x4.x * w4.x + x4.y * w4.y + x4.z * w4.z + x4.w * w4.w;
    }
    f.qv[v * HID + t] = s;
  }
}

__launch_bounds__(256)
__global__ void k_post_a(PArgs f) {
  __shared__ SMu sm;
  const int t = threadIdx.x;
  int bx = blockIdx.x;
  if (bx >= NN / 64) { vtail(sm, t, bx - NN / 64, f); return; }
  const int m0 = bx * 64;
  stage_A(sm.a.Ah, sm.a.Al, t, f.agg, m0, 1);
  __syncthreads();
  f32x4 acc[2][4] = {};
  mfma_pass(sm.a.Ah, sm.a.Al, t, f.WaF_l, acc);
  const int w = t >> 6, c16 = t & 15, quad = (t & 63) >> 4;
  float g = sigmoid_f(*f.skip_l0), gm1 = 1.0f - g;
  #pragma unroll
  for (int j = 0; j < 2; ++j) {
    const int col = (2 * w + j) * 16 + c16;
    const float bb = f.ba_l0[col];
    #pragma unroll
    for (int s = 0; s < 4; ++s)
      #pragma unroll
      for (int r = 0; r < 4; ++r) {
        int lm = 16 * s + quad * 4 + r;
        float v = acc[j][s][r] + bb;
        f.xcur[(size_t)(m0 + lm) * HID + col] =
            g * v + gm1 * f.xold[(size_t)(m0 + lm) * HID + col];
      }
  }
}

// ================= k_post_b: next-layer proj slices from xop_cur (1-2 passes/block) ===========
__launch_bounds__(256)
__global__ void k_post_b(const float* __restrict__ X, const unsigned short* __restrict__ WqF,
                         const unsigned short* __restrict__ CWF,
                         const float* __restrict__ bq0, const float* __restrict__ CBl,
                         float* __restrict__ Pq, unsigned int* __restrict__ Pkv0,
                         unsigned int* __restrict__ Pkv1, int y_base) {
  __shared__ SMu sm;
  const int t = threadIdx.x;
  int y = y_base + (blockIdx.x >> 9), tile = blockIdx.x & 511;
  int m0 = tile * 64;
  stage_A(sm.a.Ah, sm.a.Al, t, X, m0, 0);
  __syncthreads();
  if (y == 0)      proj_q (sm.a.Ah, sm.a.Al, t, m0, WqF, bq0, Pq);
  else if (y == 1) proj_kv(sm.a.Ah, sm.a.Al, t, m0, CWF, CBl, CBl + HID, Pkv0);
  else             proj_kv(sm.a.Ah, sm.a.Al, t, m0, CWF + (size_t)2 * 32768,
                           CBl + 2 * HID, CBl + 3 * HID, Pkv1);
}

// ================= k_tail: l=3 edge1-agg (in-block, 4 wave-slots) + vnode post + JK/MLP =======
// Replaces l3 k_edges + l3 vtail + k_final (3 launches -> 1); xv/outsv[3] stores become dead.
struct TailW {
  const float *win, *bin, *wout, *bout;
  const float *nw0, *nb0, *nw1, *nb1, *nw2, *nb2, *nw3, *nb3, *nw4, *nb4, *nw5, *nb5, *nw6, *nb6;
  const float *gw0, *gb0, *gw1, *gb1;
};

struct TailArgs {
  const unsigned int* Pkv1; const int *cnt1, *colB1;
  const float* qv;
  const float *Wa_l1, *ba_l1, *skip_l1, *xvold;   // layer-3 vnode post
  const float* outsv;                              // layers 0..2
  TailW tw;
  float* outp;
};

__launch_bounds__(256)
__global__ void k_tail(TailArgs a) {
  __shared__ float xs[4][HID], qq[4][HID], kk[4][HID], vv[4][HID], oo[4][HID];
  __shared__ float att[NH][4][4];
  __shared__ float hb[HID], tb[64];
  __shared__ float p0[4][64], p1[4][64], pw[4][64];
  int v = blockIdx.x, t = threadIdx.x;
  int w = t >> 6, lane = t & 63;
  // ---- edge1 aggregation for vnode v (4 wave-slots) ----
  {
    float2 q = *(const float2*)(a.qv + v * HID + 2 * lane);
    int tot = a.cnt1[v]; if (tot > CAP1) tot = CAP1;
    int base = v << 10;
    int len = (tot + 3) >> 2;
    int s0 = base + w * len;
    int s1 = s0 + len; int lim = base + tot; if (s1 > lim) s1 = lim;
    float acc0 = 0.f, acc1 = 0.f, wsum = 0.f;
    int e = s0;
    for (; e + 4 <= s1; e += 4) {
      uint2 ka = *(const uint2*)(a.Pkv1 + ((size_t)a.colB1[e]     << 7) + 2 * lane);
      uint2 kb = *(const uint2*)(a.Pkv1 + ((size_t)a.colB1[e + 1] << 7) + 2 * lane);
      uint2 kc = *(const uint2*)(a.Pkv1 + ((size_t)a.colB1[e + 2] << 7) + 2 * lane);
      uint2 kd = *(const uint2*)(a.Pkv1 + ((size_t)a.colB1[e + 3] << 7) + 2 * lane);
      float pa = q.x * f16lo(ka.x) + q.y * f16lo(ka.y);
      float pb = q.x * f16lo(kb.x) + q.y * f16lo(kb.y);
      float pc = q.x * f16lo(kc.x) + q.y * f16lo(kc.y);
      float pd = q.x * f16lo(kd.x) + q.y * f16lo(kd.y);
      pa += __shfl_xor(pa, 1); pb += __shfl_xor(pb, 1); pc += __shfl_xor(pc, 1); pd += __shfl_xor(pd, 1);
      pa += __shfl_xor(pa, 2); pb += __shfl_xor(pb, 2); pc += __shfl_xor(pc, 2); pd += __shfl_xor(pd, 2);
      pa += __shfl_xor(pa, 4); pb += __shfl_xor(pb, 4); pc += __shfl_xor(pc, 4); pd += __shfl_xor(pd, 4);
      float wa = __expf(pa), wb = __expf(pb), wc = __expf(pc), wd = __expf(pd);
      wsum += (wa + wb) + (wc + wd);
      acc0 += wa * f16hi(ka.x) + wb * f16hi(kb.x) + wc * f16hi(kc.x) + wd * f16hi(kd.x);
      acc1 += wa * f16hi(ka.y) + wb * f16hi(kb.y) + wc * f16hi(kc.y) + wd * f16hi(kd.y);
    }
    for (; e < s1; ++e) {
      uint2 kv = *(const uint2*)(a.Pkv1 + ((size_t)a.colB1[e] << 7) + 2 * lane);
      float p = q.x * f16lo(kv.x) + q.y * f16lo(kv.y);
      p += __shfl_xor(p, 1); p += __shfl_xor(p, 2); p += __shfl_xor(p, 4);
      float ww = __expf(p);
      wsum += ww; acc0 += ww * f16hi(kv.x); acc1 += ww * f16hi(kv.y);
    }
    p0[w][lane] = acc0; p1[w][lane] = acc1; pw[w][lane] = wsum;
  }
  __syncthreads();
  if (t < 64) {
    float a0 = p0[0][t] + p0[1][t] + p0[2][t] + p0[3][t];
    float a1 = p1[0][t] + p1[1][t] + p1[2][t] + p1[3][t];
    float ws = pw[0][t] + pw[1][t] + pw[2][t] + pw[3][t];
    float inv = 1.0f / (ws + 1e-16f);
    hb[2 * t]     = gelu_f(a0 * inv);
    hb[2 * t + 1] = gelu_f(a1 * inv);
  }
  __syncthreads();
  if (t < HID) {                         // layer-3 vnode post -> xs[3] (LDS only)
    float s = a.ba_l1[t];
    const float4* wr = (const float4*)(a.Wa_l1 + (size_t)t * HID);
    const float4* xx = (const float4*)hb;
    #pragma unroll 8
    for (int c = 0; c < HID / 4; ++c) {
      float4 w4 = wr[c], x4 = xx[c];
      s += x4.x * w4.x + x4.y * w4.y + x4.z * w4.z + x4.w * w4.w;
    }
    float gg = sigmoid_f(*a.skip_l1);
    xs[3][t] = gg * s + (1.f - gg) * a.xvold[v * HID + t];
    for (int l = 0; l < 3; ++l) xs[l][t] = a.outsv[(size_t)(l * NV + v) * HID + t];
  }
  __syncthreads();
  const TailW& tw = a.tw;
  if (t < HID) {
    for (int l = 0; l < 4; ++l) {
      float sq = tw.bin[t], sk = tw.bin[t + 128], sv = tw.bin[t + 256];
      const float* wq = tw.win + (size_t)t * HID;
      const float* wk = tw.win + (size_t)(t + 128) * HID;
      const float* wv = tw.win + (size_t)(t + 256) * HID;
      for (int c = 0; c < HID; ++c) {
        float x = xs[l][c];
        sq += x * wq[c]; sk += x * wk[c]; sv += x * wv[c];
      }
      qq[l][t] = sq; kk[l][t] = sk; vv[l][t] = sv;
    }
  }
  __syncthreads();
  if (t < 128) {
    int h = t >> 4, ql = (t >> 2) & 3, kl = t & 3;
    float s = 0.f;
    #pragma unroll
    for (int d = 0; d < DH; ++d) s += qq[ql][h * DH + d] * kk[kl][h * DH + d];
    att[h][ql][kl] = s * SCALE;
  }
  __syncthreads();
  if (t < 32) {
    int h = t >> 2, ql = t & 3;
    float m = att[h][ql][0];
    for (int k2 = 1; k2 < 4; ++k2) m = fmaxf(m, att[h][ql][k2]);
    float e[4], s = 0.f;
    for (int k2 = 0; k2 < 4; ++k2) { e[k2] = __expf(att[h][ql][k2] - m); s += e[k2]; }
    for (int k2 = 0; k2 < 4; ++k2) att[h][ql][k2] = e[k2] / s;
  }
  __syncthreads();
  if (t < 128) {
    int h = t >> 4;
    #pragma unroll
    for (int ql = 0; ql < 4; ++ql) {
      float s = 0.f;
      #pragma unroll
      for (int kl = 0; kl < 4; ++kl) s += att[h][ql][kl] * vv[kl][t];
      oo[ql][t] = s;
    }
  }
  __syncthreads();
  if (t < 128) {
    float s = 0.f;
    const float* wr = tw.wout + (size_t)t * HID;
    for (int l = 0; l < 4; ++l) {
      float ss = tw.bout[t];
      for (int c = 0; c < HID; ++c) ss += oo[l][c] * wr[c];
      s += ss;
    }
    hb[t] = s;
  }
  __syncthreads();
  if (t < 64) { float s = tw.nb0[t]; const float* wr = tw.nw0 + t * 128; for (int c = 0; c < 128; ++c) s += hb[c] * wr[c]; tb[t] = gelu_f(s); }
  __syncthreads();
  if (t < 32) { float s = tw.nb1[t]; const float* wr = tw.nw1 + t * 64;  for (int c = 0; c < 64;  ++c) s += tb[c] * wr[c]; hb[t] = gelu_f(s); }
  __syncthreads();
  if (t < 16) { float s = tw.nb2[t]; const float* wr = tw.nw2 + t * 32;  for (int c = 0; c < 32;  ++c) s += hb[c] * wr[c]; tb[t] = gelu_f(s); }
  __syncthreads();
  if (t < 8)  { float s = tw.nb3[t]; const float* wr = tw.nw3 + t * 16;  for (int c = 0; c < 16;  ++c) s += tb[c] * wr[c]; hb[t] = gelu_f(s); }
  __syncthreads();
  if (t < 4)  { float s = tw.nb4[t]; const float* wr = tw.nw4 + t * 8;   for (int c = 0; c < 8;   ++c) s += hb[c] * wr[c]; tb[t] = gelu_f(s); }
  __syncthreads();
  if (t < 2)  { float s = tw.nb5[t]; const float* wr = tw.nw5 + t * 4;   for (int c = 0; c < 4;   ++c) s += tb[c] * wr[c]; hb[t] = gelu_f(s); }
  __syncthreads();
  if (t == 0) {
    float s = hb[0] * tw.nw6[0] + hb[1] * tw.nw6[1] + tw.nb6[0];
    float g0 = gelu_f(s * tw.gw0[0] + tw.gb0[0]);
    float g1 = gelu_f(s * tw.gw0[1] + tw.gb0[1]);
    a.outp[v] = g0 * tw.gw1[0] + g1 * tw.gw1[1] + tw.gb1[0];
  }
}

// ================= host =======================================================================
extern "C" void kernel_launch(void* const* d_in, const int* in_sizes, int n_in,
                              void* d_out, int out_size, void* d_ws, size_t ws_size,
                              hipStream_t stream) {
  const float* x_op = (const float*)d_in[0];
  const float* x_v  = (const float*)d_in[1];
  const int*   ei0  = (const int*)d_in[2];
  const int*   ei1  = (const int*)d_in[3];
  const float* Wk   = (const float*)d_in[4];
  const float* Wq   = (const float*)d_in[5];
  const float* Wv   = (const float*)d_in[6];
  const float* Wa   = (const float*)d_in[7];
  const float* bk   = (const float*)d_in[8];
  const float* bq   = (const float*)d_in[9];
  const float* bv   = (const float*)d_in[10];
  const float* ba   = (const float*)d_in[11];
  const float* skip = (const float*)d_in[12];
  const float* a_rel = (const float*)d_in[13];
  const float* m_rel = (const float*)d_in[14];
  const float* p_rel = (const float*)d_in[15];
  (void)in_sizes; (void)n_in; (void)out_size; (void)ws_size;

  char* wsp = (char*)d_ws;
  size_t off = 0;
  auto alloc = [&](size_t bytes) -> void* {
    void* p = wsp + off;
    off += (bytes + 255) & ~(size_t)255;
    return p;
  };
  float* Pq    = (float*)alloc((size_t)NN * HID * 4);
  unsigned int* Pkv0 = (unsigned int*)alloc((size_t)NN * HID * 4);  // fp16 k|v packed per dword
  unsigned int* Pkv1 = (unsigned int*)alloc((size_t)NN * HID * 4);
  float* xopA  = (float*)alloc((size_t)NN * HID * 4);
  float* xopB  = (float*)alloc((size_t)NN * HID * 4);
  float* agg   = (float*)alloc((size_t)NN * HID * 4);
  float* CB    = (float*)alloc((size_t)16 * HID * 4);
  unsigned short* FW = (unsigned short*)alloc((size_t)24 * 32768 * 2);  // 1.57 MB frag weights
  float* xv    = (float*)alloc((size_t)NV * HID * 4);
  float* qv    = (float*)alloc((size_t)NV * HID * 4);
  float* outsv = (float*)alloc((size_t)NL * NV * HID * 4);
  float* part  = (float*)alloc((size_t)NV * 32 * 192 * 4);
  int* cnt0    = (int*)alloc((size_t)NN * 4);
  int* colB0   = (int*)alloc((size_t)NN * CAP0 * 4);
  int* cnt1    = (int*)alloc((size_t)NV * 4);
  int* colB1   = (int*)alloc((size_t)NV * CAP1 * 4);

  k_sf<<<24 + NN / 256, 256, 0, stream>>>(Wk, Wv, bk, bv, a_rel, m_rel, p_rel, Wq, Wa,
                                          CB, FW, cnt0, cnt1);

  PreArgs pa;
  pa.src0 = ei0; pa.dst0 = ei0 + E0E;
  pa.src1 = ei1; pa.dst1 = ei1 + NN;
  pa.cnt0 = cnt0; pa.cnt1 = cnt1; pa.colB0 = colB0; pa.colB1 = colB1;
  pa.x_op = x_op; pa.FW = FW; pa.bq = bq; pa.CB = CB;
  pa.Pq = Pq; pa.Pkv0 = Pkv0; pa.Pkv1 = Pkv1;
  pa.x_v = x_v; pa.Wq1 = Wq + (size_t)1 * HID * HID; pa.bq1 = bq + HID; pa.qv = qv;
  k_pre<<<E0E / 4096 + NN / 4096 + 3 * (NN / 64) + NV, 256, 0, stream>>>(pa);

  for (int l = 0; l < NL - 1; ++l) {
    k_edges<<<NN / 4 + NV * 8, 256, 0, stream>>>(Pq, Pkv0, Pkv1, cnt0, colB0, agg,
                                                 qv, cnt1, colB1, part);
    float* xold = (l == 0) ? (float*)x_op : ((l & 1) ? xopA : xopB);
    float* xcur = (l & 1) ? xopB : xopA;       // l=0->A, l=1->B, l=2->A
    PArgs f;
    f.agg = agg;
    f.WaF_l = FW + (size_t)(20 + l) * 32768;
    f.ba_l0 = ba + (l * 2 + 0) * HID;
    f.skip_l0 = skip + l * 2 + 0;
    f.xold = xold;
    f.xcur = xcur;
    f.part = part;
    f.Wa_l1 = Wa + (size_t)(l * 2 + 1) * HID * HID;
    f.ba_l1 = ba + (l * 2 + 1) * HID;
    f.skip_l1 = skip + l * 2 + 1;
    f.xvold = (l == 0) ? x_v : xv;
    f.xv = xv;
    f.outsv_l = outsv + (size_t)l * NV * HID;
    f.qv = qv;
    int ln = l + 1;
    f.Wq_n1 = Wq + (size_t)(ln * 2 + 1) * HID * HID;
    f.bq_n1 = bq + (ln * 2 + 1) * HID;
    f.do_qv = 1;
    k_post_a<<<NN / 64 + NV, 256, 0, stream>>>(f);
    // l=0,1 -> full q+kv0+kv1 (3 slices); l=2 -> only kv1 survives pruning (y_base=2)
    int nsl = (l < 2) ? 3 : 1;
    int yb  = (l < 2) ? 0 : 2;
    k_post_b<<<nsl * (NN / 64), 256, 0, stream>>>(
        xcur, FW + (size_t)(16 + ln) * 32768, FW + (size_t)(ln * 4) * 32768,
        bq + (size_t)ln * 2 * HID, CB + (size_t)ln * 4 * HID, Pq, Pkv0, Pkv1, yb);
  }

  TailArgs ta;
  ta.Pkv1 = Pkv1; ta.cnt1 = cnt1; ta.colB1 = colB1;
  ta.qv = qv;
  ta.Wa_l1 = Wa + (size_t)(3 * 2 + 1) * HID * HID;
  ta.ba_l1 = ba + (3 * 2 + 1) * HID;
  ta.skip_l1 = skip + 3 * 2 + 1;
  ta.xvold = xv;
  ta.outsv = outsv;
  ta.tw.win  = (const float*)d_in[16]; ta.tw.bin  = (const float*)d_in[17];
  ta.tw.wout = (const float*)d_in[18]; ta.tw.bout = (const float*)d_in[19];
  ta.tw.nw0 = (const float*)d_in[20]; ta.tw.nb0 = (const float*)d_in[21];
  ta.tw.nw1 = (const float*)d_in[22]; ta.tw.nb1 = (const float*)d_in[23];
  ta.tw.nw2 = (const float*)d_in[24]; ta.tw.nb2 = (const float*)d_in[25];
  ta.tw.nw3 = (const float*)d_in[26]; ta.tw.nb3 = (const float*)d_in[27];
  ta.tw.nw4 = (const float*)d_in[28]; ta.tw.nb4 = (const float*)d_in[29];
  ta.tw.nw5 = (const float*)d_in[30]; ta.tw.nb5 = (const float*)d_in[31];
  ta.tw.nw6 = (const float*)d_in[32]; ta.tw.nb6 = (const float*)d_in[33];
  ta.tw.gw0 = (const float*)d_in[34]; ta.tw.gb0 = (const float*)d_in[35];
  ta.tw.gw1 = (const float*)d_in[36]; ta.tw.gb1 = (const float*)d_in[37];
  ta.outp = (float*)d_out;
  k_tail<<<NV, 256, 0, stream>>>(ta);
}

// Round 13
// 546.373 us; speedup vs baseline: 1.3855x; 1.0180x over previous
//
#include <hip/hip_runtime.h>

#define NN   32768
#define NV   64
#define E0E  524288
#define HID  128
#define NL   4
#define NH   8
#define DH   16
#define SCALE 0.25f
#define LDA  136   // bf16 row stride for staged A (16B frag reads, 2-way alias)
#define CAP0 64
#define CAP1 1024

typedef __attribute__((ext_vector_type(8))) short short8;   // 8 bf16 = 4 VGPRs
typedef __attribute__((ext_vector_type(4))) float f32x4;

__device__ __forceinline__ float gelu_f(float x) {
  return 0.5f * x * (1.0f + erff(x * 0.7071067811865475f));
}
__device__ __forceinline__ float sigmoid_f(float x) {
  return 1.0f / (1.0f + __expf(-x));
}
__device__ __forceinline__ unsigned short f2bf(float x) {   // RN-even f32->bf16
  unsigned u = __float_as_uint(x);
  return (unsigned short)((u + 0x7FFFu + ((u >> 16) & 1u)) >> 16);
}
__device__ __forceinline__ float bf2f(unsigned short h) {
  return __uint_as_float(((unsigned)h) << 16);
}
__device__ __forceinline__ unsigned short f2h(float x) {
  union { _Float16 h; unsigned short u; } cv;
  cv.h = (_Float16)x;
  return cv.u;
}
__device__ __forceinline__ float h2f(unsigned short u) {
  union { _Float16 h; unsigned short u; } cv;
  cv.u = u;
  return (float)cv.h;
}
__device__ __forceinline__ float f16lo(unsigned u) { return h2f((unsigned short)(u & 0xffffu)); }
__device__ __forceinline__ float f16hi(unsigned u) { return h2f((unsigned short)(u >> 16)); }

union SMu {
  struct { unsigned short Ah[64][LDA]; unsigned short Al[64][LDA]; } a;  // 34816 B
  struct { float xr[HID]; float xn[HID]; } v;
};

// ---- stage 64xK=128 fp32 tile into split hi/lo bf16 LDS (coalesced float4 reads) ----
__device__ __forceinline__ void stage_A(unsigned short Ah[][LDA], unsigned short Al[][LDA],
                                        int t, const float* __restrict__ A, int m0, int gelu) {
  #pragma unroll
  for (int i = 0; i < 8; ++i) {
    int idx = t + 256 * i;            // float4 index over 64x32
    int m = idx >> 5, c4 = (idx & 31) * 4;
    float4 v = *(const float4*)(A + (size_t)(m0 + m) * HID + c4);
    if (gelu) { v.x = gelu_f(v.x); v.y = gelu_f(v.y); v.z = gelu_f(v.z); v.w = gelu_f(v.w); }
    unsigned short h0 = f2bf(v.x), h1 = f2bf(v.y), h2 = f2bf(v.z), h3 = f2bf(v.w);
    *(ushort4*)&Ah[m][c4] = make_ushort4(h0, h1, h2, h3);
    *(ushort4*)&Al[m][c4] = make_ushort4(f2bf(v.x - bf2f(h0)), f2bf(v.y - bf2f(h1)),
                                         f2bf(v.z - bf2f(h2)), f2bf(v.w - bf2f(h3)));
  }
}

// ---- MFMA split-bf16 single pass: 64x128 tile, K=128, B-reuse form (96 MFMAs/wave) ----
__device__ __forceinline__ void mfma_pass(const unsigned short Ah[][LDA],
    const unsigned short Al[][LDA], int t, const unsigned short* __restrict__ Wf,
    f32x4 acc[2][4]) {
  const int w = t >> 6, lane = t & 63, c16 = lane & 15, quad = lane >> 4;
  #pragma unroll
  for (int ks = 0; ks < 4; ++ks) {
    short8 ah[4], al[4];
    #pragma unroll
    for (int s = 0; s < 4; ++s) {
      ah[s] = *(const short8*)&Ah[16 * s + c16][ks * 32 + quad * 8];
      al[s] = *(const short8*)&Al[16 * s + c16][ks * 32 + quad * 8];
    }
    #pragma unroll
    for (int j = 0; j < 2; ++j) {
      const unsigned short* bp = Wf + (size_t)(((2 * w + j) * 4 + ks) * 64 + lane) * 8;
      short8 bh = *(const short8*)bp;
      short8 bl = *(const short8*)(bp + 16384);
      #pragma unroll
      for (int s = 0; s < 4; ++s) {
        acc[j][s] = __builtin_amdgcn_mfma_f32_16x16x32_bf16(ah[s], bh, acc[j][s], 0, 0, 0);
        acc[j][s] = __builtin_amdgcn_mfma_f32_16x16x32_bf16(ah[s], bl, acc[j][s], 0, 0, 0);
        acc[j][s] = __builtin_amdgcn_mfma_f32_16x16x32_bf16(al[s], bh, acc[j][s], 0, 0, 0);
      }
    }
  }
}

// ---- q slice: 1 pass + fp16 write (2B stores from adjacent lanes of SAME wave -> coalesced;
//      NOT the r8 trap, which was interleaved half-stores from DIFFERENT blocks) ----
__device__ __forceinline__ void proj_q(const unsigned short Ah[][LDA],
    const unsigned short Al[][LDA], int t, int m0,
    const unsigned short* __restrict__ WqF, const float* __restrict__ bq0,
    unsigned short* __restrict__ Pqh) {
  const int w = t >> 6, c16 = t & 15, quad = (t & 63) >> 4;
  f32x4 acc[2][4] = {};
  mfma_pass(Ah, Al, t, WqF, acc);
  #pragma unroll
  for (int j = 0; j < 2; ++j) {
    const int col = (2 * w + j) * 16 + c16;
    const float bb = bq0[col];
    #pragma unroll
    for (int s = 0; s < 4; ++s)
      #pragma unroll
      for (int r = 0; r < 4; ++r) {
        int m = m0 + 16 * s + quad * 4 + r;
        Pqh[(size_t)m * HID + col] = f2h(acc[j][s][r] + bb);
      }
  }
}

// ---- k|v slice: K pass (packed to 16 u32) then V pass, full-dword fp16 pair write ----
__device__ __forceinline__ void proj_kv(const unsigned short Ah[][LDA],
    const unsigned short Al[][LDA], int t, int m0,
    const unsigned short* __restrict__ WfK, const float* __restrict__ bK,
    const float* __restrict__ bV, unsigned int* __restrict__ dst) {
  const int w = t >> 6, c16 = t & 15, quad = (t & 63) >> 4;
  unsigned kp[2][4][2];
  {
    f32x4 accK[2][4] = {};
    mfma_pass(Ah, Al, t, WfK, accK);
    #pragma unroll
    for (int j = 0; j < 2; ++j) {
      const float bbk = bK[(2 * w + j) * 16 + c16];
      #pragma unroll
      for (int s = 0; s < 4; ++s)
        #pragma unroll
        for (int rr = 0; rr < 2; ++rr)
          kp[j][s][rr] = (unsigned)f2h(accK[j][s][2 * rr] + bbk)
                       | ((unsigned)f2h(accK[j][s][2 * rr + 1] + bbk) << 16);
    }
  }
  f32x4 accV[2][4] = {};
  mfma_pass(Ah, Al, t, WfK + 32768, accV);
  #pragma unroll
  for (int j = 0; j < 2; ++j) {
    const int col = (2 * w + j) * 16 + c16;
    const float bbv = bV[col];
    #pragma unroll
    for (int s = 0; s < 4; ++s)
      #pragma unroll
      for (int r = 0; r < 4; ++r) {
        int m = m0 + 16 * s + quad * 4 + r;
        unsigned pk = (kp[j][s][r >> 1] >> ((r & 1) * 16)) & 0xffffu;
        unsigned pv = (unsigned)f2h(accV[j][s][r] + bbv);
        dst[(size_t)m * HID + col] = pk | (pv << 16);
      }
  }
}

// ================= k_sf: weight-combine (via LDS) + frag + cnt zeroing, one launch ============
__global__ __launch_bounds__(256) void k_sf(
    const float* __restrict__ Wk, const float* __restrict__ Wv,
    const float* __restrict__ bk, const float* __restrict__ bv,
    const float* __restrict__ a_rel, const float* __restrict__ m_rel,
    const float* __restrict__ p_rel, const float* __restrict__ Wq,
    const float* __restrict__ Wa, float* __restrict__ CB,
    unsigned short* __restrict__ FW, int* __restrict__ cnt0, int* __restrict__ cnt1) {
  __shared__ float cwl[HID * HID];   // 64 KB
  int m = blockIdx.x, t = threadIdx.x;
  if (m >= 24) {                     // zero blocks (replaces 2 memset launches)
    int i = (m - 24) * 256 + t;
    cnt0[i] = 0;
    if (m == 24 && t < NV) cnt1[t] = 0;
    return;
  }
  unsigned short* hi = FW + (size_t)m * 32768;
  unsigned short* lo = hi + 16384;
  if (m < 16) {                      // combine K/V mats into LDS, bias to CB, then frag
    int l = m >> 2, mat = m & 3;
    int rel = mat >> 1;
    int isK = ((mat & 1) == 0);
    const float* W  = (isK ? Wk : Wv) + (size_t)(l * 2) * HID * HID;
    const float* bb = (isK ? bk : bv) + (l * 2) * HID;
    const float* R  = (isK ? a_rel : m_rel) + (size_t)((l * 2 + rel) * NH) * DH * DH;
    for (int o = t; o < HID * HID; o += 256) {
      int j = o >> 7, c = o & 127;
      int h = j >> 4, e = j & 15;
      float sc = isK ? (p_rel[(l * 2 + rel) * NH + h] * SCALE) : 1.0f;
      float s = 0.f;
      #pragma unroll
      for (int d = 0; d < DH; ++d)
        s += W[(size_t)(h * DH + d) * HID + c] * R[h * 256 + d * 16 + e];
      cwl[j * HID + c] = s * sc;
    }
    if (t < HID) {
      int j = t, h = j >> 4, e = j & 15;
      float sc = isK ? (p_rel[(l * 2 + rel) * NH + h] * SCALE) : 1.0f;
      float s = 0.f;
      #pragma unroll
      for (int d = 0; d < DH; ++d) s += bb[h * DH + d] * R[h * 256 + d * 16 + e];
      CB[m * HID + j] = s * sc;
    }
    __syncthreads();
    for (int idx = t; idx < 16384; idx += 256) {
      int j = idx & 7, lane = (idx >> 3) & 63, ks = (idx >> 9) & 3, nt = idx >> 11;
      int n = nt * 16 + (lane & 15);
      int k = ks * 32 + (lane >> 4) * 8 + j;
      float x = cwl[n * HID + k];
      unsigned short h = f2bf(x);
      hi[idx] = h;
      lo[idx] = f2bf(x - bf2f(h));
    }
    return;
  }
  const float* src = (m < 20) ? (Wq + (size_t)((m - 16) * 2) * HID * HID)
                              : (Wa + (size_t)((m - 20) * 2) * HID * HID);
  for (int idx = t; idx < 16384; idx += 256) {
    int j = idx & 7, lane = (idx >> 3) & 63, ks = (idx >> 9) & 3, nt = idx >> 11;
    int n = nt * 16 + (lane & 15);
    int k = ks * 32 + (lane >> 4) * 8 + j;
    float x = src[(size_t)n * HID + k];
    unsigned short h = f2bf(x);
    hi[idx] = h;
    lo[idx] = f2bf(x - bf2f(h));
  }
}

// ================= k_pre: bucket-scatter (16/thr ILP) + layer-0 proj slices + qv0 =============
struct PreArgs {
  const int *src0, *dst0, *src1, *dst1;
  int *cnt0, *cnt1, *colB0, *colB1;
  const float* x_op; const unsigned short* FW; const float *bq, *CB;
  unsigned short* Pqh; unsigned int *Pkv0, *Pkv1;
  const float *x_v, *Wq1, *bq1; float* qv;
};

__launch_bounds__(256)
__global__ void k_pre(PreArgs a) {
  __shared__ SMu sm;
  int bx = blockIdx.x, t = threadIdx.x;
  if (bx < E0E / 4096) {                     // edge0 bucket scatter (16 edges/thread ILP)
    int base = bx * 4096 + t;
    #pragma unroll
    for (int i = 0; i < 16; ++i) {
      int e = base + i * 256;
      int d = a.dst0[e];
      int pos = atomicAdd(&a.cnt0[d], 1);
      if (pos < CAP0) a.colB0[((size_t)d << 6) + pos] = a.src0[e];
    }
    return;
  }
  bx -= E0E / 4096;
  if (bx < NN / 4096) {                      // edge1 bucket scatter
    int base = bx * 4096 + t;
    #pragma unroll
    for (int i = 0; i < 16; ++i) {
      int e = base + i * 256;
      int d = a.dst1[e];
      int pos = atomicAdd(&a.cnt1[d], 1);
      if (pos < CAP1) a.colB1[((size_t)d << 10) + pos] = a.src1[e];
    }
    return;
  }
  bx -= NN / 4096;
  if (bx < 3 * (NN / 64)) {                  // layer-0 projection slice: tile | slice y
    int y = bx >> 9, tile = bx & 511;
    int m0 = tile * 64;
    stage_A(sm.a.Ah, sm.a.Al, t, a.x_op, m0, 0);
    __syncthreads();
    if (y == 0)      proj_q (sm.a.Ah, sm.a.Al, t, m0, a.FW + (size_t)16 * 32768, a.bq, a.Pqh);
    else if (y == 1) proj_kv(sm.a.Ah, sm.a.Al, t, m0, a.FW, a.CB, a.CB + HID, a.Pkv0);
    else             proj_kv(sm.a.Ah, sm.a.Al, t, m0, a.FW + (size_t)2 * 32768,
                             a.CB + 2 * HID, a.CB + 3 * HID, a.Pkv1);
    return;
  }
  bx -= 3 * (NN / 64);                       // qv0 for vnode bx
  if (t < HID) sm.v.xr[t] = a.x_v[bx * HID + t];
  __syncthreads();
  if (t < HID) {
    float s = a.bq1[t];
    const float4* wr = (const float4*)(a.Wq1 + (size_t)t * HID);
    const float4* xx = (const float4*)sm.v.xr;
    #pragma unroll 8
    for (int c = 0; c < HID / 4; ++c) {
      float4 w4 = wr[c], x4 = xx[c];
      s += x4.x * w4.x + x4.y * w4.y + x4.z * w4.z + x4.w * w4.w;
    }
    a.qv[bx * HID + t] = s;
  }
}

// ================= k_edges: edge0 (blocks < NN/4) + edge1 (for l=0..2) =========================
__launch_bounds__(256)
__global__ void k_edges(const unsigned int* __restrict__ Pq32,
                        const unsigned int* __restrict__ Pkv0,
                        const unsigned int* __restrict__ Pkv1,
                        const int* __restrict__ cnt0, const int* __restrict__ colB0,
                        float* __restrict__ agg, const float* __restrict__ qv,
                        const int* __restrict__ cnt1, const int* __restrict__ colB1,
                        float* __restrict__ part) {
  int lane = threadIdx.x & 63;
  if (blockIdx.x < NN / 4) {
    int n = blockIdx.x * 4 + (threadIdx.x >> 6);
    unsigned qp = Pq32[(size_t)n * 64 + lane];    // fp16 pair: dims 2*lane, 2*lane+1
    float qx = f16lo(qp), qy = f16hi(qp);
    int cnt = cnt0[n]; if (cnt > CAP0) cnt = CAP0;
    int e = n << 6, e1 = (n << 6) + cnt;
    float acc0 = 0.f, acc1 = 0.f, wsum = 0.f;
    for (; e + 8 <= e1; e += 8) {
      const uint2* r[8];
      #pragma unroll
      for (int u = 0; u < 8; ++u)
        r[u] = (const uint2*)(Pkv0 + ((size_t)colB0[e + u] << 7) + 2 * lane);
      uint2 kv[8];
      #pragma unroll
      for (int u = 0; u < 8; ++u) kv[u] = *r[u];
      float p[8];
      #pragma unroll
      for (int u = 0; u < 8; ++u)
        p[u] = qx * f16lo(kv[u].x) + qy * f16lo(kv[u].y);
      #pragma unroll
      for (int u = 0; u < 8; ++u) {
        p[u] += __shfl_xor(p[u], 1); p[u] += __shfl_xor(p[u], 2); p[u] += __shfl_xor(p[u], 4);
      }
      #pragma unroll
      for (int u = 0; u < 8; ++u) {
        float wg = __expf(p[u]);
        wsum += wg; acc0 += wg * f16hi(kv[u].x); acc1 += wg * f16hi(kv[u].y);
      }
    }
    for (; e < e1; ++e) {
      uint2 kv = *(const uint2*)(Pkv0 + ((size_t)colB0[e] << 7) + 2 * lane);
      float p = qx * f16lo(kv.x) + qy * f16lo(kv.y);
      p += __shfl_xor(p, 1); p += __shfl_xor(p, 2); p += __shfl_xor(p, 4);
      float wg = __expf(p);
      wsum += wg; acc0 += wg * f16hi(kv.x); acc1 += wg * f16hi(kv.y);
    }
    float inv = 1.0f / (wsum + 1e-16f);
    *(float2*)(agg + (size_t)n * HID + 2 * lane) = make_float2(acc0 * inv, acc1 * inv);
  } else {
    int b2 = blockIdx.x - NN / 4;
    int g = b2 >> 3, ch = b2 & 7;
    int w = threadIdx.x >> 6;
    int slot = ch * 4 + w;
    float2 q = *(const float2*)(qv + g * HID + 2 * lane);
    int tot = cnt1[g]; if (tot > CAP1) tot = CAP1;
    int base = g << 10;
    int len = (tot + 31) >> 5;
    int s0 = base + slot * len;
    int s1 = s0 + len; int lim = base + tot; if (s1 > lim) s1 = lim;
    float acc0 = 0.f, acc1 = 0.f, wsum = 0.f;
    int e = s0;
    for (; e + 4 <= s1; e += 4) {
      uint2 ka = *(const uint2*)(Pkv1 + ((size_t)colB1[e]     << 7) + 2 * lane);
      uint2 kb = *(const uint2*)(Pkv1 + ((size_t)colB1[e + 1] << 7) + 2 * lane);
      uint2 kc = *(const uint2*)(Pkv1 + ((size_t)colB1[e + 2] << 7) + 2 * lane);
      uint2 kd = *(const uint2*)(Pkv1 + ((size_t)colB1[e + 3] << 7) + 2 * lane);
      float pa = q.x * f16lo(ka.x) + q.y * f16lo(ka.y);
      float pb = q.x * f16lo(kb.x) + q.y * f16lo(kb.y);
      float pc = q.x * f16lo(kc.x) + q.y * f16lo(kc.y);
      float pd = q.x * f16lo(kd.x) + q.y * f16lo(kd.y);
      pa += __shfl_xor(pa, 1); pb += __shfl_xor(pb, 1); pc += __shfl_xor(pc, 1); pd += __shfl_xor(pd, 1);
      pa += __shfl_xor(pa, 2); pb += __shfl_xor(pb, 2); pc += __shfl_xor(pc, 2); pd += __shfl_xor(pd, 2);
      pa += __shfl_xor(pa, 4); pb += __shfl_xor(pb, 4); pc += __shfl_xor(pc, 4); pd += __shfl_xor(pd, 4);
      float wa = __expf(pa), wb = __expf(pb), wc = __expf(pc), wd = __expf(pd);
      wsum += (wa + wb) + (wc + wd);
      acc0 += wa * f16hi(ka.x) + wb * f16hi(kb.x) + wc * f16hi(kc.x) + wd * f16hi(kd.x);
      acc1 += wa * f16hi(ka.y) + wb * f16hi(kb.y) + wc * f16hi(kc.y) + wd * f16hi(kd.y);
    }
    for (; e < s1; ++e) {
      uint2 kv = *(const uint2*)(Pkv1 + ((size_t)colB1[e] << 7) + 2 * lane);
      float p = q.x * f16lo(kv.x) + q.y * f16lo(kv.y);
      p += __shfl_xor(p, 1); p += __shfl_xor(p, 2); p += __shfl_xor(p, 4);
      float ww = __expf(p);
      wsum += ww; acc0 += ww * f16hi(kv.x); acc1 += ww * f16hi(kv.y);
    }
    float* pp = part + (size_t)(g * 32 + slot) * 192;
    pp[lane] = acc0; pp[64 + lane] = acc1; pp[128 + lane] = wsum;
  }
}

// ================= k_post_a: post-GEMM + skip -> xop_cur (1 pass/block) + vtail ===============
struct PArgs {
  const float *agg; const unsigned short *WaF_l; const float *ba_l0, *skip_l0, *xold;
  float *xcur;
  const float *part, *Wa_l1, *ba_l1, *skip_l1, *xvold;
  float *xv, *outsv_l, *qv;
  const float *Wq_n1, *bq_n1;
  int do_qv;
};

__device__ __forceinline__ void vtail(SMu& sm, int t, int v, const PArgs& f) {
  if (t < 64) {
    float a0 = 0.f, a1 = 0.f, ws2 = 0.f;
    for (int s = 0; s < 32; ++s) {
      const float* p = f.part + (size_t)(v * 32 + s) * 192;
      a0 += p[t]; a1 += p[64 + t]; ws2 += p[128 + t];
    }
    float inv = 1.0f / (ws2 + 1e-16f);
    sm.v.xr[2 * t]     = gelu_f(a0 * inv);
    sm.v.xr[2 * t + 1] = gelu_f(a1 * inv);
  }
  __syncthreads();
  if (t < HID) {
    float s = f.ba_l1[t];
    const float4* wr = (const float4*)(f.Wa_l1 + (size_t)t * HID);
    const float4* xx = (const float4*)sm.v.xr;
    #pragma unroll 8
    for (int c = 0; c < HID / 4; ++c) {
      float4 w4 = wr[c], x4 = xx[c];
      s += x4.x * w4.x + x4.y * w4.y + x4.z * w4.z + x4.w * w4.w;
    }
    float gg = sigmoid_f(*f.skip_l1);
    float nv2 = gg * s + (1.f - gg) * f.xvold[v * HID + t];
    f.xv[v * HID + t] = nv2;
    f.outsv_l[v * HID + t] = nv2;
    sm.v.xn[t] = nv2;
  }
  __syncthreads();
  if (f.do_qv && t < HID) {
    float s = f.bq_n1[t];
    const float4* wr = (const float4*)(f.Wq_n1 + (size_t)t * HID);
    const float4* xx = (const float4*)sm.v.xn;
    #pragma unroll 8
    for (int c = 0; c < HID / 4; ++c) {
      float4 w4 = wr[c], x4 = xx[c];
      s += x4.x * w4.x + x4.y * w4.y + x4.z * w4.z + x4.w * w4.w;
    }
    f.qv[v * HID + t] = s;
  }
}

__launch_bounds__(256)
__global__ void k_post_a(PArgs f) {
  __shared__ SMu sm;
  const int t = threadIdx.x;
  int bx = blockIdx.x;
  if (bx >= NN / 64) { vtail(sm, t, bx - NN / 64, f); return; }
  const int m0 = bx * 64;
  stage_A(sm.a.Ah, sm.a.Al, t, f.agg, m0, 1);
  __syncthreads();
  f32x4 acc[2][4] = {};
  mfma_pass(sm.a.Ah, sm.a.Al, t, f.WaF_l, acc);
  const int w = t >> 6, c16 = t & 15, quad = (t & 63) >> 4;
  float g = sigmoid_f(*f.skip_l0), gm1 = 1.0f - g;
  #pragma unroll
  for (int j = 0; j < 2; ++j) {
    const int col = (2 * w + j) * 16 + c16;
    const float bb = f.ba_l0[col];
    #pragma unroll
    for (int s = 0; s < 4; ++s)
      #pragma unroll
      for (int r = 0; r < 4; ++r) {
        int lm = 16 * s + quad * 4 + r;
        float v = acc[j][s][r] + bb;
        f.xcur[(size_t)(m0 + lm) * HID + col] =
            g * v + gm1 * f.xold[(size_t)(m0 + lm) * HID + col];
      }
  }
}

// ================= k_post_b: next-layer proj slices from xop_cur (1-2 passes/block) ===========
__launch_bounds__(256)
__global__ void k_post_b(const float* __restrict__ X, const unsigned short* __restrict__ WqF,
                         const unsigned short* __restrict__ CWF,
                         const float* __restrict__ bq0, const float* __restrict__ CBl,
                         unsigned short* __restrict__ Pqh, unsigned int* __restrict__ Pkv0,
                         unsigned int* __restrict__ Pkv1, int y_base) {
  __shared__ SMu sm;
  const int t = threadIdx.x;
  int y = y_base + (blockIdx.x >> 9), tile = blockIdx.x & 511;
  int m0 = tile * 64;
  stage_A(sm.a.Ah, sm.a.Al, t, X, m0, 0);
  __syncthreads();
  if (y == 0)      proj_q (sm.a.Ah, sm.a.Al, t, m0, WqF, bq0, Pqh);
  else if (y == 1) proj_kv(sm.a.Ah, sm.a.Al, t, m0, CWF, CBl, CBl + HID, Pkv0);
  else             proj_kv(sm.a.Ah, sm.a.Al, t, m0, CWF + (size_t)2 * 32768,
                           CBl + 2 * HID, CBl + 3 * HID, Pkv1);
}

// ================= k_tail: l=3 edge1-agg (in-block, 4 wave-slots, ILP-8) + post + JK/MLP ======
struct TailW {
  const float *win, *bin, *wout, *bout;
  const float *nw0, *nb0, *nw1, *nb1, *nw2, *nb2, *nw3, *nb3, *nw4, *nb4, *nw5, *nb5, *nw6, *nb6;
  const float *gw0, *gb0, *gw1, *gb1;
};

struct TailArgs {
  const unsigned int* Pkv1; const int *cnt1, *colB1;
  const float* qv;
  const float *Wa_l1, *ba_l1, *skip_l1, *xvold;   // layer-3 vnode post
  const float* outsv;                              // layers 0..2
  TailW tw;
  float* outp;
};

__launch_bounds__(256)
__global__ void k_tail(TailArgs a) {
  __shared__ float xs[4][HID], qq[4][HID], kk[4][HID], vv[4][HID], oo[4][HID];
  __shared__ float att[NH][4][4];
  __shared__ float hb[HID], tb[64];
  __shared__ float p0[4][64], p1[4][64], pw[4][64];
  int v = blockIdx.x, t = threadIdx.x;
  int w = t >> 6, lane = t & 63;
  // ---- edge1 aggregation for vnode v (4 wave-slots, 8-deep gather ILP: only 256 waves on
  //      the whole device here, so per-wave MLP is the lever) ----
  {
    float2 q = *(const float2*)(a.qv + v * HID + 2 * lane);
    int tot = a.cnt1[v]; if (tot > CAP1) tot = CAP1;
    int base = v << 10;
    int len = (tot + 3) >> 2;
    int s0 = base + w * len;
    int s1 = s0 + len; int lim = base + tot; if (s1 > lim) s1 = lim;
    float acc0 = 0.f, acc1 = 0.f, wsum = 0.f;
    int e = s0;
    for (; e + 8 <= s1; e += 8) {
      uint2 kv[8];
      #pragma unroll
      for (int u = 0; u < 8; ++u)
        kv[u] = *(const uint2*)(a.Pkv1 + ((size_t)a.colB1[e + u] << 7) + 2 * lane);
      float p[8];
      #pragma unroll
      for (int u = 0; u < 8; ++u)
        p[u] = q.x * f16lo(kv[u].x) + q.y * f16lo(kv[u].y);
      #pragma unroll
      for (int u = 0; u < 8; ++u) {
        p[u] += __shfl_xor(p[u], 1); p[u] += __shfl_xor(p[u], 2); p[u] += __shfl_xor(p[u], 4);
      }
      #pragma unroll
      for (int u = 0; u < 8; ++u) {
        float wg = __expf(p[u]);
        wsum += wg; acc0 += wg * f16hi(kv[u].x); acc1 += wg * f16hi(kv[u].y);
      }
    }
    for (; e < s1; ++e) {
      uint2 kv = *(const uint2*)(a.Pkv1 + ((size_t)a.colB1[e] << 7) + 2 * lane);
      float p = q.x * f16lo(kv.x) + q.y * f16lo(kv.y);
      p += __shfl_xor(p, 1); p += __shfl_xor(p, 2); p += __shfl_xor(p, 4);
      float ww = __expf(p);
      wsum += ww; acc0 += ww * f16hi(kv.x); acc1 += ww * f16hi(kv.y);
    }
    p0[w][lane] = acc0; p1[w][lane] = acc1; pw[w][lane] = wsum;
  }
  __syncthreads();
  if (t < 64) {
    float a0 = p0[0][t] + p0[1][t] + p0[2][t] + p0[3][t];
    float a1 = p1[0][t] + p1[1][t] + p1[2][t] + p1[3][t];
    float ws = pw[0][t] + pw[1][t] + pw[2][t] + pw[3][t];
    float inv = 1.0f / (ws + 1e-16f);
    hb[2 * t]     = gelu_f(a0 * inv);
    hb[2 * t + 1] = gelu_f(a1 * inv);
  }
  __syncthreads();
  if (t < HID) {                         // layer-3 vnode post -> xs[3] (LDS only)
    float s = a.ba_l1[t];
    const float4* wr = (const float4*)(a.Wa_l1 + (size_t)t * HID);
    const float4* xx = (const float4*)hb;
    #pragma unroll 8
    for (int c = 0; c < HID / 4; ++c) {
      float4 w4 = wr[c], x4 = xx[c];
      s += x4.x * w4.x + x4.y * w4.y + x4.z * w4.z + x4.w * w4.w;
    }
    float gg = sigmoid_f(*a.skip_l1);
    xs[3][t] = gg * s + (1.f - gg) * a.xvold[v * HID + t];
    for (int l = 0; l < 3; ++l) xs[l][t] = a.outsv[(size_t)(l * NV + v) * HID + t];
  }
  __syncthreads();
  const TailW& tw = a.tw;
  if (t < HID) {
    for (int l = 0; l < 4; ++l) {
      float sq = tw.bin[t], sk = tw.bin[t + 128], sv = tw.bin[t + 256];
      const float* wq = tw.win + (size_t)t * HID;
      const float* wk = tw.win + (size_t)(t + 128) * HID;
      const float* wv = tw.win + (size_t)(t + 256) * HID;
      for (int c = 0; c < HID; ++c) {
        float x = xs[l][c];
        sq += x * wq[c]; sk += x * wk[c]; sv += x * wv[c];
      }
      qq[l][t] = sq; kk[l][t] = sk; vv[l][t] = sv;
    }
  }
  __syncthreads();
  if (t < 128) {
    int h = t >> 4, ql = (t >> 2) & 3, kl = t & 3;
    float s = 0.f;
    #pragma unroll
    for (int d = 0; d < DH; ++d) s += qq[ql][h * DH + d] * kk[kl][h * DH + d];
    att[h][ql][kl] = s * SCALE;
  }
  __syncthreads();
  if (t < 32) {
    int h = t >> 2, ql = t & 3;
    float m = att[h][ql][0];
    for (int k2 = 1; k2 < 4; ++k2) m = fmaxf(m, att[h][ql][k2]);
    float e[4], s = 0.f;
    for (int k2 = 0; k2 < 4; ++k2) { e[k2] = __expf(att[h][ql][k2] - m); s += e[k2]; }
    for (int k2 = 0; k2 < 4; ++k2) att[h][ql][k2] = e[k2] / s;
  }
  __syncthreads();
  if (t < 128) {
    int h = t >> 4;
    #pragma unroll
    for (int ql = 0; ql < 4; ++ql) {
      float s = 0.f;
      #pragma unroll
      for (int kl = 0; kl < 4; ++kl) s += att[h][ql][kl] * vv[kl][t];
      oo[ql][t] = s;
    }
  }
  __syncthreads();
  if (t < 128) {
    float s = 0.f;
    const float* wr = tw.wout + (size_t)t * HID;
    for (int l = 0; l < 4; ++l) {
      float ss = tw.bout[t];
      for (int c = 0; c < HID; ++c) ss += oo[l][c] * wr[c];
      s += ss;
    }
    hb[t] = s;
  }
  __syncthreads();
  if (t < 64) { float s = tw.nb0[t]; const float* wr = tw.nw0 + t * 128; for (int c = 0; c < 128; ++c) s += hb[c] * wr[c]; tb[t] = gelu_f(s); }
  __syncthreads();
  if (t < 32) { float s = tw.nb1[t]; const float* wr = tw.nw1 + t * 64;  for (int c = 0; c < 64;  ++c) s += tb[c] * wr[c]; hb[t] = gelu_f(s); }
  __syncthreads();
  if (t < 16) { float s = tw.nb2[t]; const float* wr = tw.nw2 + t * 32;  for (int c = 0; c < 32;  ++c) s += hb[c] * wr[c]; tb[t] = gelu_f(s); }
  __syncthreads();
  if (t < 8)  { float s = tw.nb3[t]; const float* wr = tw.nw3 + t * 16;  for (int c = 0; c < 16;  ++c) s += tb[c] * wr[c]; hb[t] = gelu_f(s); }
  __syncthreads();
  if (t < 4)  { float s = tw.nb4[t]; const float* wr = tw.nw4 + t * 8;   for (int c = 0; c < 8;   ++c) s += hb[c] * wr[c]; tb[t] = gelu_f(s); }
  __syncthreads();
  if (t < 2)  { float s = tw.nb5[t]; const float* wr = tw.nw5 + t * 4;   for (int c = 0; c < 4;   ++c) s += tb[c] * wr[c]; hb[t] = gelu_f(s); }
  __syncthreads();
  if (t == 0) {
    float s = hb[0] * tw.nw6[0] + hb[1] * tw.nw6[1] + tw.nb6[0];
    float g0 = gelu_f(s * tw.gw0[0] + tw.gb0[0]);
    float g1 = gelu_f(s * tw.gw0[1] + tw.gb0[1]);
    a.outp[v] = g0 * tw.gw1[0] + g1 * tw.gw1[1] + tw.gb1[0];
  }
}

// ================= host =======================================================================
extern "C" void kernel_launch(void* const* d_in, const int* in_sizes, int n_in,
                              void* d_out, int out_size, void* d_ws, size_t ws_size,
                              hipStream_t stream) {
  const float* x_op = (const float*)d_in[0];
  const float* x_v  = (const float*)d_in[1];
  const int*   ei0  = (const int*)d_in[2];
  const int*   ei1  = (const int*)d_in[3];
  const float* Wk   = (const float*)d_in[4];
  const float* Wq   = (const float*)d_in[5];
  const float* Wv   = (const float*)d_in[6];
  const float* Wa   = (const float*)d_in[7];
  const float* bk   = (const float*)d_in[8];
  const float* bq   = (const float*)d_in[9];
  const float* bv   = (const float*)d_in[10];
  const float* ba   = (const float*)d_in[11];
  const float* skip = (const float*)d_in[12];
  const float* a_rel = (const float*)d_in[13];
  const float* m_rel = (const float*)d_in[14];
  const float* p_rel = (const float*)d_in[15];
  (void)in_sizes; (void)n_in; (void)out_size; (void)ws_size;

  char* wsp = (char*)d_ws;
  size_t off = 0;
  auto alloc = [&](size_t bytes) -> void* {
    void* p = wsp + off;
    off += (bytes + 255) & ~(size_t)255;
    return p;
  };
  unsigned short* Pqh = (unsigned short*)alloc((size_t)NN * HID * 2);  // fp16 q
  unsigned int* Pkv0 = (unsigned int*)alloc((size_t)NN * HID * 4);  // fp16 k|v packed per dword
  unsigned int* Pkv1 = (unsigned int*)alloc((size_t)NN * HID * 4);
  float* xopA  = (float*)alloc((size_t)NN * HID * 4);
  float* xopB  = (float*)alloc((size_t)NN * HID * 4);
  float* agg   = (float*)alloc((size_t)NN * HID * 4);
  float* CB    = (float*)alloc((size_t)16 * HID * 4);
  unsigned short* FW = (unsigned short*)alloc((size_t)24 * 32768 * 2);  // 1.57 MB frag weights
  float* xv    = (float*)alloc((size_t)NV * HID * 4);
  float* qv    = (float*)alloc((size_t)NV * HID * 4);
  float* outsv = (float*)alloc((size_t)NL * NV * HID * 4);
  float* part  = (float*)alloc((size_t)NV * 32 * 192 * 4);
  int* cnt0    = (int*)alloc((size_t)NN * 4);
  int* colB0   = (int*)alloc((size_t)NN * CAP0 * 4);
  int* cnt1    = (int*)alloc((size_t)NV * 4);
  int* colB1   = (int*)alloc((size_t)NV * CAP1 * 4);

  k_sf<<<24 + NN / 256, 256, 0, stream>>>(Wk, Wv, bk, bv, a_rel, m_rel, p_rel, Wq, Wa,
                                          CB, FW, cnt0, cnt1);

  PreArgs pa;
  pa.src0 = ei0; pa.dst0 = ei0 + E0E;
  pa.src1 = ei1; pa.dst1 = ei1 + NN;
  pa.cnt0 = cnt0; pa.cnt1 = cnt1; pa.colB0 = colB0; pa.colB1 = colB1;
  pa.x_op = x_op; pa.FW = FW; pa.bq = bq; pa.CB = CB;
  pa.Pqh = Pqh; pa.Pkv0 = Pkv0; pa.Pkv1 = Pkv1;
  pa.x_v = x_v; pa.Wq1 = Wq + (size_t)1 * HID * HID; pa.bq1 = bq + HID; pa.qv = qv;
  k_pre<<<E0E / 4096 + NN / 4096 + 3 * (NN / 64) + NV, 256, 0, stream>>>(pa);

  for (int l = 0; l < NL - 1; ++l) {
    k_edges<<<NN / 4 + NV * 8, 256, 0, stream>>>((const unsigned int*)Pqh, Pkv0, Pkv1,
                                                 cnt0, colB0, agg, qv, cnt1, colB1, part);
    float* xold = (l == 0) ? (float*)x_op : ((l & 1) ? xopA : xopB);
    float* xcur = (l & 1) ? xopB : xopA;       // l=0->A, l=1->B, l=2->A
    PArgs f;
    f.agg = agg;
    f.WaF_l = FW + (size_t)(20 + l) * 32768;
    f.ba_l0 = ba + (l * 2 + 0) * HID;
    f.skip_l0 = skip + l * 2 + 0;
    f.xold = xold;
    f.xcur = xcur;
    f.part = part;
    f.Wa_l1 = Wa + (size_t)(l * 2 + 1) * HID * HID;
    f.ba_l1 = ba + (l * 2 + 1) * HID;
    f.skip_l1 = skip + l * 2 + 1;
    f.xvold = (l == 0) ? x_v : xv;
    f.xv = xv;
    f.outsv_l = outsv + (size_t)l * NV * HID;
    f.qv = qv;
    int ln = l + 1;
    f.Wq_n1 = Wq + (size_t)(ln * 2 + 1) * HID * HID;
    f.bq_n1 = bq + (ln * 2 + 1) * HID;
    f.do_qv = 1;
    k_post_a<<<NN / 64 + NV, 256, 0, stream>>>(f);
    // l=0,1 -> full q+kv0+kv1 (3 slices); l=2 -> only kv1 survives pruning (y_base=2)
    int nsl = (l < 2) ? 3 : 1;
    int yb  = (l < 2) ? 0 : 2;
    k_post_b<<<nsl * (NN / 64), 256, 0, stream>>>(
        xcur, FW + (size_t)(16 + ln) * 32768, FW + (size_t)(ln * 4) * 32768,
        bq + (size_t)ln * 2 * HID, CB + (size_t)ln * 4 * HID, Pqh, Pkv0, Pkv1, yb);
  }

  TailArgs ta;
  ta.Pkv1 = Pkv1; ta.cnt1 = cnt1; ta.colB1 = colB1;
  ta.qv = qv;
  ta.Wa_l1 = Wa + (size_t)(3 * 2 + 1) * HID * HID;
  ta.ba_l1 = ba + (3 * 2 + 1) * HID;
  ta.skip_l1 = skip + 3 * 2 + 1;
  ta.xvold = xv;
  ta.outsv = outsv;
  ta.tw.win  = (const float*)d_in[16]; ta.tw.bin  = (const float*)d_in[17];
  ta.tw.wout = (const float*)d_in[18]; ta.tw.bout = (const float*)d_in[19];
  ta.tw.nw0 = (const float*)d_in[20]; ta.tw.nb0 = (const float*)d_in[21];
  ta.tw.nw1 = (const float*)d_in[22]; ta.tw.nb1 = (const float*)d_in[23];
  ta.tw.nw2 = (const float*)d_in[24]; ta.tw.nb2 = (const float*)d_in[25];
  ta.tw.nw3 = (const float*)d_in[26]; ta.tw.nb3 = (const float*)d_in[27];
  ta.tw.nw4 = (const float*)d_in[28]; ta.tw.nb4 = (const float*)d_in[29];
  ta.tw.nw5 = (const float*)d_in[30]; ta.tw.nb5 = (const float*)d_in[31];
  ta.tw.nw6 = (const float*)d_in[32]; ta.tw.nb6 = (const float*)d_in[33];
  ta.tw.gw0 = (const float*)d_in[34]; ta.tw.gb0 = (const float*)d_in[35];
  ta.tw.gw1 = (const float*)d_in[36]; ta.tw.gb1 = (const float*)d_in[37];
  ta.outp = (float*)d_out;
  k_tail<<<NV, 256, 0, stream>>>(ta);
}